// Round 15
// baseline (993.887 us; speedup 1.0000x reference)
//
#include <hip/hip_runtime.h>
#include <hip/hip_bf16.h>

typedef __attribute__((ext_vector_type(8))) short short8;
typedef __attribute__((ext_vector_type(4))) float f32x4;
using bf16 = __hip_bfloat16;

// N=50000, OP=128, H=256, H2=128, OUT=128
// xbuf concat: [pred 0 | succ 128 | res 256 | mat 320 | item 352 | self 480], 608

__device__ __forceinline__ short f2bf(float f) {
  union { float f; unsigned u; } v; v.f = f;
  unsigned r = (v.u + 0x7fffu + ((v.u >> 16) & 1u)) >> 16;  // RNE
  return (short)r;
}
__device__ __forceinline__ float bf2f(short s) {
  union { unsigned u; float f; } x;
  x.u = ((unsigned)(unsigned short)s) << 16;
  return x.f;
}

// ---------------------------------------------------------------------------
// Weight descriptor (needed by prep)
// ---------------------------------------------------------------------------
struct WDesc { const float* src; int K; int C; int dstoff; };
struct WDescs14 { WDesc w[14]; };

// ---------------------------------------------------------------------------
// Fused preprocessing: y=0 cvt ops, y=1 cvt items, y=2 wconv (14 mats in x),
// y=3 zero tmp.
// ---------------------------------------------------------------------------
struct PrepArgs {
  const float* ops_src; bf16* ops_dst; int nops4;
  const float* items_src; bf16* items_dst; int nitems4;
  WDescs14 wd; short* wf;
  int* tmp; int ntmp;
};

__global__ __launch_bounds__(256) void prep_kernel(PrepArgs P) {
  const int bx = blockIdx.x;
  switch (blockIdx.y) {
    case 0: {
      int i = bx * 256 + threadIdx.x;
      if (i >= P.nops4) return;
      f32x4 v = *reinterpret_cast<const f32x4*>(P.ops_src + (size_t)i * 4);
      uint2 u;
      u.x = (unsigned)(unsigned short)f2bf(v.x) | ((unsigned)(unsigned short)f2bf(v.y) << 16);
      u.y = (unsigned)(unsigned short)f2bf(v.z) | ((unsigned)(unsigned short)f2bf(v.w) << 16);
      *reinterpret_cast<uint2*>(P.ops_dst + (size_t)i * 4) = u;
    } break;
    case 1: {
      int i = bx * 256 + threadIdx.x;
      if (i >= P.nitems4) return;
      f32x4 v = *reinterpret_cast<const f32x4*>(P.items_src + (size_t)i * 4);
      uint2 u;
      u.x = (unsigned)(unsigned short)f2bf(v.x) | ((unsigned)(unsigned short)f2bf(v.y) << 16);
      u.y = (unsigned)(unsigned short)f2bf(v.z) | ((unsigned)(unsigned short)f2bf(v.w) << 16);
      *reinterpret_cast<uint2*>(P.items_dst + (size_t)i * 4) = u;
    } break;
    case 2: {
      if (bx >= 76 * 14) return;
      WDesc d = P.wd.w[bx / 76];
      int KC = d.K >> 5, CT = d.C >> 4;
      int t = (bx % 76) * 256 + threadIdx.x;
      if (t >= KC * CT * 64) return;
      int lane = t & 63, tile = t >> 6;
      int kc = tile / CT, ct = tile - kc * CT;
      int g = lane >> 4, lp = lane & 15;
      short8 v;
#pragma unroll
      for (int j = 0; j < 8; ++j)
        v[j] = f2bf(d.src[(size_t)(kc * 32 + g * 8 + j) * d.C + ct * 16 + lp]);
      *reinterpret_cast<short8*>(P.wf + d.dstoff + (size_t)t * 8) = v;
    } break;
    default: {
      int i = bx * 256 + threadIdx.x;
      if (i < P.ntmp) P.tmp[i] = 0;
    } break;
  }
}

// ---------------------------------------------------------------------------
// CSR build structures
// ---------------------------------------------------------------------------
struct EdgeList { const int* dst; const int* src; int* counts; int* col; int E; };
struct EdgeLists4 { EdgeList l[4]; };

// vectorized: 4 edges/thread
__global__ __launch_bounds__(256) void count4v_kernel(EdgeLists4 ls) {
  EdgeList l = ls.l[blockIdx.y];
  int e0 = (blockIdx.x * 256 + threadIdx.x) * 4;
  if (e0 + 4 <= l.E) {
    int4 d = *reinterpret_cast<const int4*>(l.dst + e0);
    atomicAdd(&l.counts[d.x], 1);
    atomicAdd(&l.counts[d.y], 1);
    atomicAdd(&l.counts[d.z], 1);
    atomicAdd(&l.counts[d.w], 1);
  } else {
    for (int e = e0; e < l.E; ++e) atomicAdd(&l.counts[l.dst[e]], 1);
  }
}

// ---- per-1024-chunk RAW sums for the 4 count arrays ----
__global__ __launch_bounds__(256) void chunksum_kernel(
    const int* __restrict__ counts, int* __restrict__ bsum, int n, int nchunk) {
  const int t = blockIdx.y;
  const int* cnt = counts + (size_t)t * n;
  int base = blockIdx.x * 1024;
  int s = 0;
  for (int j = threadIdx.x; j < 1024; j += 256) {
    int i = base + j;
    if (i < n) s += cnt[i];
  }
#pragma unroll
  for (int off = 32; off > 0; off >>= 1) s += __shfl_down(s, off, 64);
  __shared__ int ws[4];
  const int lane = threadIdx.x & 63, wid = threadIdx.x >> 6;
  if (lane == 0) ws[wid] = s;
  __syncthreads();
  if (threadIdx.x == 0)
    bsum[(size_t)t * nchunk + blockIdx.x] = ws[0] + ws[1] + ws[2] + ws[3];
}

// ---- fused scan: per-block base + intra-chunk scan; writes offs, cursor,
//      and (for lists 0,1) per-128-row bucket cursors for the partition ----
__global__ __launch_bounds__(1024) void scanfinal2_kernel(
    const int* __restrict__ counts, const int* __restrict__ bsum,
    int* __restrict__ offsets, int* __restrict__ cursor,
    int* __restrict__ bcur, int n, int nchunk) {
  const int t = blockIdx.y;
  const int* cnt = counts + (size_t)t * n;
  __shared__ int wsum[16];
  __shared__ int base_s;
  const int lane = threadIdx.x & 63, wid = threadIdx.x >> 6;
  if (wid == 0) {
    int b = (lane < blockIdx.x) ? bsum[(size_t)t * nchunk + lane] : 0;  // nchunk<=64
#pragma unroll
    for (int off = 32; off > 0; off >>= 1) b += __shfl_down(b, off, 64);
    if (lane == 0) base_s = b;
  }
  int i = blockIdx.x * 1024 + threadIdx.x;
  int v = (i < n) ? cnt[i] : 0;
  int x = v;
#pragma unroll
  for (int off = 1; off < 64; off <<= 1) {
    int u = __shfl_up(x, off, 64);
    if (lane >= off) x += u;
  }
  if (lane == 63) wsum[wid] = x;
  __syncthreads();
  if (wid == 0 && lane < 16) {
    int w = wsum[lane];
#pragma unroll
    for (int off = 1; off < 16; off <<= 1) {
      int u = __shfl_up(w, off, 16);
      if (lane >= off) w += u;
    }
    wsum[lane] = w;
  }
  __syncthreads();
  int wpre = (wid == 0) ? 0 : wsum[wid - 1];
  int val = base_s + wpre + x - v;
  if (i < n) {
    offsets[(size_t)t * (n + 1) + i] = val;
    cursor[(size_t)t * n + i] = val;
    if (i == n - 1) offsets[(size_t)t * (n + 1) + n] = val + v;
    if (t < 2 && (i & 127) == 0) bcur[t * 512 + (i >> 7)] = val;
  }
}

// ---- bucketed partition for pred/succ: scatter packed edges into per-bucket
//      regions (391 sequential streams -> dense line writes) ----
struct Part2Args {
  const int *dst0, *src0, *dst1, *src1;
  int* bcur;            // [2*512]
  unsigned *scr0, *scr1;
  int E;
};

__global__ __launch_bounds__(256) void partition2_kernel(Part2Args P) {
  const int* dst = blockIdx.y ? P.dst1 : P.dst0;
  const int* src = blockIdx.y ? P.src1 : P.src0;
  unsigned* scr = blockIdx.y ? P.scr1 : P.scr0;
  int* bcur = P.bcur + blockIdx.y * 512;
  int e0 = (blockIdx.x * 256 + threadIdx.x) * 4;
  if (e0 + 4 <= P.E) {
    int4 d = *reinterpret_cast<const int4*>(dst + e0);
    int4 s = *reinterpret_cast<const int4*>(src + e0);
    int p0 = atomicAdd(&bcur[d.x >> 7], 1);
    int p1 = atomicAdd(&bcur[d.y >> 7], 1);
    int p2 = atomicAdd(&bcur[d.z >> 7], 1);
    int p3 = atomicAdd(&bcur[d.w >> 7], 1);
    scr[p0] = ((unsigned)d.x << 16) | (unsigned)s.x;
    scr[p1] = ((unsigned)d.y << 16) | (unsigned)s.y;
    scr[p2] = ((unsigned)d.z << 16) | (unsigned)s.z;
    scr[p3] = ((unsigned)d.w << 16) | (unsigned)s.w;
  } else {
    for (int e = e0; e < P.E; ++e) {
      int dd = dst[e];
      int p = atomicAdd(&bcur[dd >> 7], 1);
      scr[p] = ((unsigned)dd << 16) | (unsigned)src[e];
    }
  }
}

// ---- local fill: one block per 128-row bucket; col writes land in an ~8 KB
//      window -> L2-dense ----
struct FillLocalArgs {
  const unsigned *scr0, *scr1;
  const int *offs0, *offs1;
  int *cur0, *cur1;
  int *col0, *col1;
  int n;
};

__global__ __launch_bounds__(256) void filllocal_kernel(FillLocalArgs F) {
  const unsigned* scr = blockIdx.y ? F.scr1 : F.scr0;
  const int* offs = blockIdx.y ? F.offs1 : F.offs0;
  int* cur = blockIdx.y ? F.cur1 : F.cur0;
  int* col = blockIdx.y ? F.col1 : F.col0;
  int r0 = blockIdx.x << 7;
  int r1 = r0 + 128;
  if (r1 > F.n) r1 = F.n;
  int beg = offs[r0], end = offs[r1];
  for (int i = beg + (int)threadIdx.x; i < end; i += 256) {
    unsigned pk = scr[i];
    int d = (int)(pk >> 16);
    int s = (int)(pk & 0xffffu);
    int p = atomicAdd(&cur[d], 1);
    col[p] = s;
  }
}

// vectorized fill: 4 edges/thread (used for the small res/mat lists)
__global__ __launch_bounds__(256) void fill4v_kernel(EdgeLists4 ls) {
  EdgeList l = ls.l[blockIdx.y];
  int e0 = (blockIdx.x * 256 + threadIdx.x) * 4;
  if (e0 + 4 <= l.E) {
    int4 d = *reinterpret_cast<const int4*>(l.dst + e0);
    int4 s = *reinterpret_cast<const int4*>(l.src + e0);
    int p0 = atomicAdd(&l.counts[d.x], 1);
    int p1 = atomicAdd(&l.counts[d.y], 1);
    int p2 = atomicAdd(&l.counts[d.z], 1);
    int p3 = atomicAdd(&l.counts[d.w], 1);
    l.col[p0] = s.x;
    l.col[p1] = s.y;
    l.col[p2] = s.z;
    l.col[p3] = s.w;
  } else {
    for (int e = e0; e < l.E; ++e) {
      int p = atomicAdd(&l.counts[l.dst[e]], 1);
      l.col[p] = l.src[e];
    }
  }
}

// ---------------------------------------------------------------------------
// Aggregate device bodies (proven R12 logic, verbatim)
// ---------------------------------------------------------------------------
__device__ __forceinline__ void agg128_dev(
    const bf16* __restrict__ tab, const int* __restrict__ col,
    const int* __restrict__ offs, bf16* __restrict__ out, int n) {
  const int lane = threadIdx.x & 63;
  const int wid = threadIdx.x >> 6;
  const int r = blockIdx.x * 4 + wid;
  if (r >= n) return;
  const int slot = lane >> 4, lp = lane & 15;
  const int beg = offs[r], end = offs[r + 1];
  float acc[8] = {0.f, 0.f, 0.f, 0.f, 0.f, 0.f, 0.f, 0.f};
  float acc2[8] = {0.f, 0.f, 0.f, 0.f, 0.f, 0.f, 0.f, 0.f};
  float acc3[8] = {0.f, 0.f, 0.f, 0.f, 0.f, 0.f, 0.f, 0.f};
  float acc4[8] = {0.f, 0.f, 0.f, 0.f, 0.f, 0.f, 0.f, 0.f};
  int e = beg;
  for (; e + 16 <= end; e += 16) {
    int c0 = col[e + slot];
    int c1 = col[e + 4 + slot];
    int c2 = col[e + 8 + slot];
    int c3 = col[e + 12 + slot];
    short8 v0 = *reinterpret_cast<const short8*>(tab + (size_t)c0 * 128 + lp * 8);
    short8 v1 = *reinterpret_cast<const short8*>(tab + (size_t)c1 * 128 + lp * 8);
    short8 v2 = *reinterpret_cast<const short8*>(tab + (size_t)c2 * 128 + lp * 8);
    short8 v3 = *reinterpret_cast<const short8*>(tab + (size_t)c3 * 128 + lp * 8);
#pragma unroll
    for (int j = 0; j < 8; ++j) {
      acc[j] += bf2f(v0[j]);
      acc2[j] += bf2f(v1[j]);
      acc3[j] += bf2f(v2[j]);
      acc4[j] += bf2f(v3[j]);
    }
  }
  for (; e + 8 <= end; e += 8) {
    int c0 = col[e + slot];
    int c1 = col[e + 4 + slot];
    short8 v0 = *reinterpret_cast<const short8*>(tab + (size_t)c0 * 128 + lp * 8);
    short8 v1 = *reinterpret_cast<const short8*>(tab + (size_t)c1 * 128 + lp * 8);
#pragma unroll
    for (int j = 0; j < 8; ++j) {
      acc[j] += bf2f(v0[j]);
      acc2[j] += bf2f(v1[j]);
    }
  }
  for (; e < end; e += 4) {
    int idx = e + slot;
    if (idx < end) {
      int cc = col[idx];
      short8 v = *reinterpret_cast<const short8*>(tab + (size_t)cc * 128 + lp * 8);
#pragma unroll
      for (int j = 0; j < 8; ++j) acc[j] += bf2f(v[j]);
    }
  }
#pragma unroll
  for (int j = 0; j < 8; ++j) acc[j] = (acc[j] + acc2[j]) + (acc3[j] + acc4[j]);
#pragma unroll
  for (int j = 0; j < 8; ++j) {
    acc[j] += __shfl_xor(acc[j], 16, 64);
    acc[j] += __shfl_xor(acc[j], 32, 64);
  }
  if (slot == 0) {
    short8 sv;
#pragma unroll
    for (int j = 0; j < 8; ++j) sv[j] = f2bf(acc[j]);
    *reinterpret_cast<short8*>(out + (size_t)r * 128 + lp * 8) = sv;
  }
}

template <int D, int LPR>
__device__ __forceinline__ void agg_small_dev(
    const float* __restrict__ tab, const int* __restrict__ col,
    const int* __restrict__ offsets, bf16* __restrict__ out, int n) {
  constexpr int RPB = 256 / LPR;
  const int lane = threadIdx.x % LPR;
  const int r = blockIdx.x * RPB + threadIdx.x / LPR;
  if (r >= n) return;
  const int beg = offsets[r], end = offsets[r + 1];
  float2 acc = make_float2(0.f, 0.f);
  for (int e = beg; e < end; ++e) {
    int s = col[e];
    float2 v = *reinterpret_cast<const float2*>(tab + (size_t)s * D + lane * 2);
    acc.x += v.x;
    acc.y += v.y;
  }
  unsigned u = (unsigned)(unsigned short)f2bf(acc.x) |
               ((unsigned)(unsigned short)f2bf(acc.y) << 16);
  *reinterpret_cast<unsigned*>(out + (size_t)r * D + lane * 2) = u;
}

// merged aggregate: y=0 pred, y=1 succ, y=2 res, y=3 mat
struct AggArgs {
  const bf16* ops_tab;
  const float* res_tab;
  const float* mat_tab;
  const int *col_pred, *col_succ, *col_res, *col_mat;
  const int *offs_pred, *offs_succ, *offs_res, *offs_mat;
  bf16 *agg_pred, *agg_succ, *agg_res, *agg_mat;
  int n;
};

__global__ __launch_bounds__(256) void agg_all_kernel(AggArgs A) {
  switch (blockIdx.y) {
    case 0: agg128_dev(A.ops_tab, A.col_pred, A.offs_pred, A.agg_pred, A.n); break;
    case 1: agg128_dev(A.ops_tab, A.col_succ, A.offs_succ, A.agg_succ, A.n); break;
    case 2: agg_small_dev<64, 32>(A.res_tab, A.col_res, A.offs_res, A.agg_res, A.n); break;
    default: agg_small_dev<32, 16>(A.mat_tab, A.col_mat, A.offs_mat, A.agg_mat, A.n); break;
  }
}

// ---------------------------------------------------------------------------
// MFMA fused 2-layer MLP device body (bf16 in, bf16 out, wave-private LDS)
// FROZEN AT R8 — byte-for-byte. Do NOT restructure (R5/R6/R9/R10 all failed).
// ---------------------------------------------------------------------------
template <int K, int O, bool GATHER>
__device__ __forceinline__ void mlp2_dev(
    const bf16* __restrict__ X, const int* __restrict__ gidx,
    const short* __restrict__ W1f, const float* __restrict__ B1,
    const short* __restrict__ W2f, const float* __restrict__ B2,
    bf16* __restrict__ xbuf, int ooff, int tile, int lane, char* hw) {
  constexpr int KC = K / 32;
  constexpr int KC2 = 8;
  constexpr int OT = O / 16;
  const int g = lane >> 4, lp = lane & 15;
  const int row0 = tile * 16;

  short8 a[KC];
  {
    int srow = GATHER ? gidx[row0 + lp] : (row0 + lp);
    const bf16* xp = X + (size_t)srow * K + g * 8;
#pragma unroll
    for (int kc = 0; kc < KC; ++kc)
      a[kc] = *reinterpret_cast<const short8*>(xp + kc * 32);
  }

#pragma unroll
  for (int ct = 0; ct < 16; ++ct) {
    float bv = B1[ct * 16 + lp];
    f32x4 acc = {bv, bv, bv, bv};
#pragma unroll
    for (int kc = 0; kc < KC; ++kc) {
      short8 b = *reinterpret_cast<const short8*>(
          W1f + ((size_t)(kc * 16 + ct) * 64 + lane) * 8);
      acc = __builtin_amdgcn_mfma_f32_16x16x32_bf16(a[kc], b, acc, 0, 0, 0);
    }
#pragma unroll
    for (int r = 0; r < 4; ++r) {
      int rr = g * 4 + r;
      int byte = rr * 512 + (ct * 16 + lp) * 2;
      byte ^= (rr & 7) << 4;
      *reinterpret_cast<short*>(hw + byte) = f2bf(fmaxf(acc[r], 0.f));
    }
  }
  asm volatile("s_waitcnt lgkmcnt(0)" ::: "memory");
  __builtin_amdgcn_sched_barrier(0);

  short8 a2[KC2];
#pragma unroll
  for (int kc = 0; kc < KC2; ++kc) {
    int byte = lp * 512 + (kc * 32 + g * 8) * 2;
    byte ^= (lp & 7) << 4;
    a2[kc] = *reinterpret_cast<const short8*>(hw + byte);
  }
#pragma unroll
  for (int ot = 0; ot < OT; ++ot) {
    float bv = B2[ot * 16 + lp];
    f32x4 acc = {bv, bv, bv, bv};
#pragma unroll
    for (int kc = 0; kc < KC2; ++kc) {
      short8 b = *reinterpret_cast<const short8*>(
          W2f + ((size_t)(kc * OT + ot) * 64 + lane) * 8);
      acc = __builtin_amdgcn_mfma_f32_16x16x32_bf16(a2[kc], b, acc, 0, 0, 0);
    }
#pragma unroll
    for (int r = 0; r < 4; ++r) {
      int rr = g * 4 + r;
      *reinterpret_cast<short*>(xbuf + (size_t)(row0 + rr) * 608 + ooff + ot * 16 + lp) =
          f2bf(acc[r]);
    }
  }
}

struct Mlp6Args {
  const bf16 *agg_pred, *agg_succ, *agg_res, *agg_mat, *items_bf, *ops_bf;
  const int* related;
  const short* wf;
  const float *b_pred1, *b_pred2, *b_succ1, *b_succ2, *b_res1, *b_res2;
  const float *b_mat1, *b_mat2, *b_item1, *b_item2, *b_self1, *b_self2;
  bf16* xbuf;
  int ntiles;
};

__global__ __launch_bounds__(256) void mlp6_kernel(Mlp6Args A) {
  __shared__ short hbuf[4 * 16 * 256];  // 32 KB, 8 KB/wave
  const int lane = threadIdx.x & 63, wid = threadIdx.x >> 6;
  int tile = blockIdx.x * 4 + wid;
  if (tile >= A.ntiles) tile = A.ntiles - 1;  // dup benign
  char* hw = (char*)(hbuf + wid * (16 * 256));
  const short* wf = A.wf;
  switch (blockIdx.y) {
    case 0: mlp2_dev<128, 128, false>(A.agg_pred, nullptr, wf + 65536, A.b_pred1,
                                      wf + 221184, A.b_pred2, A.xbuf, 0, tile, lane, hw); break;
    case 1: mlp2_dev<128, 128, false>(A.agg_succ, nullptr, wf + 98304, A.b_succ1,
                                      wf + 253952, A.b_succ2, A.xbuf, 128, tile, lane, hw); break;
    case 2: mlp2_dev<64, 64, false>(A.agg_res, nullptr, wf + 131072, A.b_res1,
                                    wf + 286720, A.b_res2, A.xbuf, 256, tile, lane, hw); break;
    case 3: mlp2_dev<32, 32, false>(A.agg_mat, nullptr, wf + 147456, A.b_mat1,
                                    wf + 303104, A.b_mat2, A.xbuf, 320, tile, lane, hw); break;
    case 4: mlp2_dev<128, 128, true>(A.items_bf, A.related, wf + 32768, A.b_item1,
                                     wf + 188416, A.b_item2, A.xbuf, 352, tile, lane, hw); break;
    default: mlp2_dev<128, 128, false>(A.ops_bf, nullptr, wf + 0, A.b_self1,
                                       wf + 155648, A.b_self2, A.xbuf, 480, tile, lane, hw); break;
  }
}

// ---------------------------------------------------------------------------
// Final combiner: FROZEN AT R8 — byte-for-byte.
// ---------------------------------------------------------------------------
__global__ __launch_bounds__(256, 4) void final_kernel(
    const bf16* __restrict__ xbuf,
    const short* __restrict__ Wc1f, const float* __restrict__ B1,
    const short* __restrict__ Wc2f, const float* __restrict__ B2,
    const float* __restrict__ W3, const float* __restrict__ B3,
    float* __restrict__ out, int ntiles) {
  __shared__ short hbuf[4 * 16 * 256];  // 32 KB: per-wave h1 bf16, then h2 f32 aliased
  const int lane = threadIdx.x & 63, wid = threadIdx.x >> 6;
  int tile = blockIdx.x * 4 + wid;
  if (tile >= ntiles) tile = ntiles - 1;
  const int g = lane >> 4, lp = lane & 15;
  const int row0 = tile * 16;
  char* hw = (char*)(hbuf + wid * (16 * 256));

  // ---- L1: h1 = relu(x @ Wc1 + b1), 608->256, MFMA ----
  {
    const bf16* xp = xbuf + (size_t)(row0 + lp) * 608 + g * 8;
    short8 a[19];
#pragma unroll
    for (int kc = 0; kc < 19; ++kc)
      a[kc] = *reinterpret_cast<const short8*>(xp + kc * 32);
#pragma unroll
    for (int ct = 0; ct < 16; ++ct) {
      float bv = B1[ct * 16 + lp];
      f32x4 acc = {bv, bv, bv, bv};
#pragma unroll
      for (int kc = 0; kc < 19; ++kc) {
        short8 b = *reinterpret_cast<const short8*>(
            Wc1f + ((size_t)(kc * 16 + ct) * 64 + lane) * 8);
        acc = __builtin_amdgcn_mfma_f32_16x16x32_bf16(a[kc], b, acc, 0, 0, 0);
      }
#pragma unroll
      for (int r = 0; r < 4; ++r) {
        int rr = g * 4 + r;
        int byte = rr * 512 + (ct * 16 + lp) * 2;
        byte ^= (rr & 7) << 4;
        *reinterpret_cast<short*>(hw + byte) = f2bf(fmaxf(acc[r], 0.f));
      }
    }
  }
  asm volatile("s_waitcnt lgkmcnt(0)" ::: "memory");
  __builtin_amdgcn_sched_barrier(0);

  // ---- L2: h2 = relu(h1 @ Wc2 + b2), 256->128, MFMA ----
  {
    short8 a2[8];
#pragma unroll
    for (int kc = 0; kc < 8; ++kc) {
      int byte = lp * 512 + (kc * 32 + g * 8) * 2;
      byte ^= (lp & 7) << 4;
      a2[kc] = *reinterpret_cast<const short8*>(hw + byte);
    }
    asm volatile("s_waitcnt lgkmcnt(0)" ::: "memory");
    __builtin_amdgcn_sched_barrier(0);
    float* h2 = (float*)hw;  // alias over h1 (a2 fully in regs)
#pragma unroll
    for (int ot = 0; ot < 8; ++ot) {
      float bv = B2[ot * 16 + lp];
      f32x4 acc = {bv, bv, bv, bv};
#pragma unroll
      for (int kc = 0; kc < 8; ++kc) {
        short8 b = *reinterpret_cast<const short8*>(
            Wc2f + ((size_t)(kc * 8 + ot) * 64 + lane) * 8);
        acc = __builtin_amdgcn_mfma_f32_16x16x32_bf16(a2[kc], b, acc, 0, 0, 0);
      }
#pragma unroll
      for (int r = 0; r < 4; ++r)
        h2[(g * 4 + r) * 128 + ot * 16 + lp] = fmaxf(acc[r], 0.f);
    }
  }
  asm volatile("s_waitcnt lgkmcnt(0)" ::: "memory");
  __builtin_amdgcn_sched_barrier(0);

  // ---- L3: out = h2 @ W3 + b3, f32 VALU (precision-critical) ----
  {
    const float* h2 = (const float*)hw;
    const int half = lane >> 5;
    const int c = (lane & 31) * 4;
    const int rbase = half * 8;
    f32x4 acc3[8];
    f32x4 bv = *reinterpret_cast<const f32x4*>(B3 + c);
#pragma unroll
    for (int rr = 0; rr < 8; ++rr) acc3[rr] = bv;
    for (int k0 = 0; k0 < 128; k0 += 4) {
      f32x4 w0 = *reinterpret_cast<const f32x4*>(W3 + (size_t)(k0 + 0) * 128 + c);
      f32x4 w1 = *reinterpret_cast<const f32x4*>(W3 + (size_t)(k0 + 1) * 128 + c);
      f32x4 w2v = *reinterpret_cast<const f32x4*>(W3 + (size_t)(k0 + 2) * 128 + c);
      f32x4 w3v = *reinterpret_cast<const f32x4*>(W3 + (size_t)(k0 + 3) * 128 + c);
#pragma unroll
      for (int rr = 0; rr < 8; ++rr) {
        f32x4 h = *reinterpret_cast<const f32x4*>(&h2[(rbase + rr) * 128 + k0]);
        acc3[rr] += h.x * w0 + h.y * w1 + h.z * w2v + h.w * w3v;
      }
    }
#pragma unroll
    for (int rr = 0; rr < 8; ++rr)
      *reinterpret_cast<f32x4*>(out + (size_t)(row0 + rbase + rr) * 128 + c) = acc3[rr];
  }
}

// ---------------------------------------------------------------------------
// kernel_launch
// ---------------------------------------------------------------------------
extern "C" void kernel_launch(void* const* d_in, const int* in_sizes, int n_in,
                              void* d_out, int out_size, void* d_ws,
                              size_t ws_size, hipStream_t stream) {
  const float* operations = (const float*)d_in[0];
  const float* items      = (const float*)d_in[1];
  const float* materials  = (const float*)d_in[2];
  const float* resources  = (const float*)d_in[3];
  const int* related      = (const int*)d_in[4];
  const int* res_op       = (const int*)d_in[5];
  const int* res_res      = (const int*)d_in[6];
  const int* mat_op       = (const int*)d_in[7];
  const int* mat_mat      = (const int*)d_in[8];
  const int* prec_src     = (const int*)d_in[9];
  const int* prec_dst     = (const int*)d_in[10];
  const float* w_self1 = (const float*)d_in[11];
  const float* b_self1 = (const float*)d_in[12];
  const float* w_self2 = (const float*)d_in[13];
  const float* b_self2 = (const float*)d_in[14];
  const float* w_item1 = (const float*)d_in[15];
  const float* b_item1 = (const float*)d_in[16];
  const float* w_item2 = (const float*)d_in[17];
  const float* b_item2 = (const float*)d_in[18];
  const float* w_pred1 = (const float*)d_in[19];
  const float* b_pred1 = (const float*)d_in[20];
  const float* w_pred2 = (const float*)d_in[21];
  const float* b_pred2 = (const float*)d_in[22];
  const float* w_succ1 = (const float*)d_in[23];
  const float* b_succ1 = (const float*)d_in[24];
  const float* w_succ2 = (const float*)d_in[25];
  const float* b_succ2 = (const float*)d_in[26];
  const float* w_res1  = (const float*)d_in[27];
  const float* b_res1  = (const float*)d_in[28];
  const float* w_res2  = (const float*)d_in[29];
  const float* b_res2  = (const float*)d_in[30];
  const float* w_mat1  = (const float*)d_in[31];
  const float* b_mat1  = (const float*)d_in[32];
  const float* w_mat2  = (const float*)d_in[33];
  const float* b_mat2  = (const float*)d_in[34];
  const float* w_c1    = (const float*)d_in[35];
  const float* b_c1    = (const float*)d_in[36];
  const float* w_c2    = (const float*)d_in[37];
  const float* b_c2    = (const float*)d_in[38];
  const float* w_c3    = (const float*)d_in[39];
  const float* b_c3    = (const float*)d_in[40];

  const int N = in_sizes[0] / 128;   // 50000
  const int NI = in_sizes[1] / 128;  // 20000
  const int E_RES = in_sizes[5];
  const int E_MAT = in_sizes[7];
  const int E_PREC = in_sizes[9];

  // ---- ws layout ----
  size_t off = 0;
  auto take = [&](size_t bytes) {
    size_t o = off;
    off += (bytes + 63) & ~(size_t)63;
    return o;
  };
  size_t xbuf_off  = take((size_t)N * 608 * 2);
  size_t aggp_off  = take((size_t)N * 128 * 2);
  size_t aggsu_off = take((size_t)N * 128 * 2);
  size_t aggr_off  = take((size_t)N * 64 * 2);
  size_t aggm_off  = take((size_t)N * 32 * 2);
  size_t wf_off    = take((size_t)499712 * 2);
  size_t opsb_off  = take((size_t)N * 128 * 2);
  size_t itemb_off = take((size_t)NI * 128 * 2);
  size_t offs_off  = take((size_t)4 * (N + 1) * 4);
  size_t tmp_off   = take((size_t)4 * N * 4);
  size_t cols_off  = take(((size_t)2 * E_PREC + E_RES + E_MAT) * 4);
  size_t bsum_off  = take((size_t)4 * 64 * 4);
  size_t bcur_off  = take((size_t)2 * 512 * 4);
  size_t scr_off   = take((size_t)2 * E_PREC * 4);

  char* ws = (char*)d_ws;
  bf16* xbuf = (bf16*)(ws + xbuf_off);
  bf16* agg_pred = (bf16*)(ws + aggp_off);
  bf16* agg_succ = (bf16*)(ws + aggsu_off);
  bf16* agg_res  = (bf16*)(ws + aggr_off);
  bf16* agg_mat  = (bf16*)(ws + aggm_off);
  short* wf = (short*)(ws + wf_off);
  bf16* ops_bf   = (bf16*)(ws + opsb_off);
  bf16* items_bf = (bf16*)(ws + itemb_off);
  int* offs = (int*)(ws + offs_off);
  int* tmp  = (int*)(ws + tmp_off);
  int* cols = (int*)(ws + cols_off);
  int* bsum = (int*)(ws + bsum_off);
  int* bcur = (int*)(ws + bcur_off);
  unsigned* scr = (unsigned*)(ws + scr_off);

  int* offs_pred = offs;
  int* offs_succ = offs + (N + 1);
  int* offs_res  = offs + 2 * (N + 1);
  int* offs_mat  = offs + 3 * (N + 1);
  int* cur_pred = tmp;
  int* cur_succ = tmp + N;
  int* cur_res  = tmp + 2 * N;
  int* cur_mat  = tmp + 3 * N;
  int* col_pred = cols;
  int* col_succ = col_pred + E_PREC;
  int* col_res  = col_succ + E_PREC;
  int* col_mat  = col_res + E_RES;
  unsigned* scr_pred = scr;
  unsigned* scr_succ = scr + E_PREC;

  dim3 blk(256);

  // ---- fused preprocessing: cvt ops/items + wconv + zero tmp ----
  PrepArgs pp;
  pp.ops_src = operations; pp.ops_dst = ops_bf; pp.nops4 = N * 128 / 4;
  pp.items_src = items; pp.items_dst = items_bf; pp.nitems4 = NI * 128 / 4;
  pp.wd.w[0]  = {w_self1, 128, 256, 0};
  pp.wd.w[1]  = {w_item1, 128, 256, 32768};
  pp.wd.w[2]  = {w_pred1, 128, 256, 65536};
  pp.wd.w[3]  = {w_succ1, 128, 256, 98304};
  pp.wd.w[4]  = {w_res1,   64, 256, 131072};
  pp.wd.w[5]  = {w_mat1,   32, 256, 147456};
  pp.wd.w[6]  = {w_self2, 256, 128, 155648};
  pp.wd.w[7]  = {w_item2, 256, 128, 188416};
  pp.wd.w[8]  = {w_pred2, 256, 128, 221184};
  pp.wd.w[9]  = {w_succ2, 256, 128, 253952};
  pp.wd.w[10] = {w_res2,  256,  64, 286720};
  pp.wd.w[11] = {w_mat2,  256,  32, 303104};
  pp.wd.w[12] = {w_c1,    608, 256, 311296};
  pp.wd.w[13] = {w_c2,    256, 128, 466944};
  pp.wf = wf;
  pp.tmp = tmp; pp.ntmp = 4 * N;
  int prepx = (pp.nops4 + 255) / 256;  // 6250, covers all slices
  prep_kernel<<<dim3(prepx, 4), blk, 0, stream>>>(pp);

  // ---- CSR build ----
  EdgeLists4 els;
  els.l[0] = {prec_src, prec_dst, cur_pred, col_pred, E_PREC};
  els.l[1] = {prec_dst, prec_src, cur_succ, col_succ, E_PREC};
  els.l[2] = {res_op, res_res, cur_res, col_res, E_RES};
  els.l[3] = {mat_op, mat_mat, cur_mat, col_mat, E_MAT};
  int cgx = (E_PREC / 4 + 255) / 256;  // 4 edges/thread
  count4v_kernel<<<dim3(cgx, 4), blk, 0, stream>>>(els);
  int nchunk = (N + 1023) / 1024;  // 49
  chunksum_kernel<<<dim3(nchunk, 4), blk, 0, stream>>>(tmp, bsum, N, nchunk);
  scanfinal2_kernel<<<dim3(nchunk, 4), dim3(1024), 0, stream>>>(
      tmp, bsum, offs, tmp, bcur, N, nchunk);

  // bucketed fill for pred/succ
  Part2Args pa;
  pa.dst0 = prec_src; pa.src0 = prec_dst;
  pa.dst1 = prec_dst; pa.src1 = prec_src;
  pa.bcur = bcur; pa.scr0 = scr_pred; pa.scr1 = scr_succ; pa.E = E_PREC;
  partition2_kernel<<<dim3(cgx, 2), blk, 0, stream>>>(pa);
  int nbuckets = (N + 127) / 128;  // 391
  FillLocalArgs fl;
  fl.scr0 = scr_pred; fl.scr1 = scr_succ;
  fl.offs0 = offs_pred; fl.offs1 = offs_succ;
  fl.cur0 = cur_pred; fl.cur1 = cur_succ;
  fl.col0 = col_pred; fl.col1 = col_succ;
  fl.n = N;
  filllocal_kernel<<<dim3(nbuckets, 2), blk, 0, stream>>>(fl);

  // small lists: direct fill
  EdgeLists4 els2;
  els2.l[0] = {res_op, res_res, cur_res, col_res, E_RES};
  els2.l[1] = {mat_op, mat_mat, cur_mat, col_mat, E_MAT};
  els2.l[2] = els2.l[0];
  els2.l[3] = els2.l[1];
  int cgx2 = (E_RES / 4 + 255) / 256;
  fill4v_kernel<<<dim3(cgx2, 2), blk, 0, stream>>>(els2);

  // ---- aggregates ----
  AggArgs aa;
  aa.ops_tab = ops_bf; aa.res_tab = resources; aa.mat_tab = materials;
  aa.col_pred = col_pred; aa.col_succ = col_succ; aa.col_res = col_res; aa.col_mat = col_mat;
  aa.offs_pred = offs_pred; aa.offs_succ = offs_succ; aa.offs_res = offs_res; aa.offs_mat = offs_mat;
  aa.agg_pred = agg_pred; aa.agg_succ = agg_succ; aa.agg_res = agg_res; aa.agg_mat = agg_mat;
  aa.n = N;
  agg_all_kernel<<<dim3((N + 3) / 4, 4), blk, 0, stream>>>(aa);

  // ---- 6 MLPs in one launch ----
  int ntiles = N / 16;           // 3125
  int mgrid = (ntiles + 3) / 4;  // 782
  Mlp6Args ma;
  ma.agg_pred = agg_pred; ma.agg_succ = agg_succ; ma.agg_res = agg_res; ma.agg_mat = agg_mat;
  ma.items_bf = items_bf; ma.ops_bf = ops_bf; ma.related = related; ma.wf = wf;
  ma.b_pred1 = b_pred1; ma.b_pred2 = b_pred2; ma.b_succ1 = b_succ1; ma.b_succ2 = b_succ2;
  ma.b_res1 = b_res1; ma.b_res2 = b_res2; ma.b_mat1 = b_mat1; ma.b_mat2 = b_mat2;
  ma.b_item1 = b_item1; ma.b_item2 = b_item2; ma.b_self1 = b_self1; ma.b_self2 = b_self2;
  ma.xbuf = xbuf; ma.ntiles = ntiles;
  mlp6_kernel<<<dim3(mgrid, 6), blk, 0, stream>>>(ma);

  // ---- final combiner ----
  final_kernel<<<mgrid, blk, 0, stream>>>(
      xbuf, wf + 311296, b_c1, wf + 466944, b_c2, w_c3, b_c3, (float*)d_out, ntiles);
}

// Round 16
// 525.068 us; speedup vs baseline: 1.8929x; 1.8929x over previous
//
#include <hip/hip_runtime.h>
#include <hip/hip_bf16.h>

typedef __attribute__((ext_vector_type(8))) short short8;
typedef __attribute__((ext_vector_type(4))) float f32x4;
using bf16 = __hip_bfloat16;

// N=50000, OP=128, H=256, H2=128, OUT=128
// xbuf concat: [pred 0 | succ 128 | res 256 | mat 320 | item 352 | self 480], 608

__device__ __forceinline__ short f2bf(float f) {
  union { float f; unsigned u; } v; v.f = f;
  unsigned r = (v.u + 0x7fffu + ((v.u >> 16) & 1u)) >> 16;  // RNE
  return (short)r;
}
__device__ __forceinline__ float bf2f(short s) {
  union { unsigned u; float f; } x;
  x.u = ((unsigned)(unsigned short)s) << 16;
  return x.f;
}

// ---------------------------------------------------------------------------
// Weight descriptor (needed by prep)
// ---------------------------------------------------------------------------
struct WDesc { const float* src; int K; int C; int dstoff; };
struct WDescs14 { WDesc w[14]; };

// ---------------------------------------------------------------------------
// Fused preprocessing: y=0 cvt ops, y=1 cvt items, y=2 wconv (14 mats in x),
// y=3 zero tmp.
// ---------------------------------------------------------------------------
struct PrepArgs {
  const float* ops_src; bf16* ops_dst; int nops4;
  const float* items_src; bf16* items_dst; int nitems4;
  WDescs14 wd; short* wf;
  int* tmp; int ntmp;
};

__global__ __launch_bounds__(256) void prep_kernel(PrepArgs P) {
  const int bx = blockIdx.x;
  switch (blockIdx.y) {
    case 0: {
      int i = bx * 256 + threadIdx.x;
      if (i >= P.nops4) return;
      f32x4 v = *reinterpret_cast<const f32x4*>(P.ops_src + (size_t)i * 4);
      uint2 u;
      u.x = (unsigned)(unsigned short)f2bf(v.x) | ((unsigned)(unsigned short)f2bf(v.y) << 16);
      u.y = (unsigned)(unsigned short)f2bf(v.z) | ((unsigned)(unsigned short)f2bf(v.w) << 16);
      *reinterpret_cast<uint2*>(P.ops_dst + (size_t)i * 4) = u;
    } break;
    case 1: {
      int i = bx * 256 + threadIdx.x;
      if (i >= P.nitems4) return;
      f32x4 v = *reinterpret_cast<const f32x4*>(P.items_src + (size_t)i * 4);
      uint2 u;
      u.x = (unsigned)(unsigned short)f2bf(v.x) | ((unsigned)(unsigned short)f2bf(v.y) << 16);
      u.y = (unsigned)(unsigned short)f2bf(v.z) | ((unsigned)(unsigned short)f2bf(v.w) << 16);
      *reinterpret_cast<uint2*>(P.items_dst + (size_t)i * 4) = u;
    } break;
    case 2: {
      if (bx >= 76 * 14) return;
      WDesc d = P.wd.w[bx / 76];
      int KC = d.K >> 5, CT = d.C >> 4;
      int t = (bx % 76) * 256 + threadIdx.x;
      if (t >= KC * CT * 64) return;
      int lane = t & 63, tile = t >> 6;
      int kc = tile / CT, ct = tile - kc * CT;
      int g = lane >> 4, lp = lane & 15;
      short8 v;
#pragma unroll
      for (int j = 0; j < 8; ++j)
        v[j] = f2bf(d.src[(size_t)(kc * 32 + g * 8 + j) * d.C + ct * 16 + lp]);
      *reinterpret_cast<short8*>(P.wf + d.dstoff + (size_t)t * 8) = v;
    } break;
    default: {
      int i = bx * 256 + threadIdx.x;
      if (i < P.ntmp) P.tmp[i] = 0;
    } break;
  }
}

// ---------------------------------------------------------------------------
// CSR build structures
// ---------------------------------------------------------------------------
struct EdgeList { const int* dst; const int* src; int* counts; int* col; int E; };
struct EdgeLists4 { EdgeList l[4]; };

// vectorized: 4 edges/thread
__global__ __launch_bounds__(256) void count4v_kernel(EdgeLists4 ls) {
  EdgeList l = ls.l[blockIdx.y];
  int e0 = (blockIdx.x * 256 + threadIdx.x) * 4;
  if (e0 + 4 <= l.E) {
    int4 d = *reinterpret_cast<const int4*>(l.dst + e0);
    atomicAdd(&l.counts[d.x], 1);
    atomicAdd(&l.counts[d.y], 1);
    atomicAdd(&l.counts[d.z], 1);
    atomicAdd(&l.counts[d.w], 1);
  } else {
    for (int e = e0; e < l.E; ++e) atomicAdd(&l.counts[l.dst[e]], 1);
  }
}

// ---- per-1024-chunk RAW sums for the 4 count arrays ----
__global__ __launch_bounds__(256) void chunksum_kernel(
    const int* __restrict__ counts, int* __restrict__ bsum, int n, int nchunk) {
  const int t = blockIdx.y;
  const int* cnt = counts + (size_t)t * n;
  int base = blockIdx.x * 1024;
  int s = 0;
  for (int j = threadIdx.x; j < 1024; j += 256) {
    int i = base + j;
    if (i < n) s += cnt[i];
  }
#pragma unroll
  for (int off = 32; off > 0; off >>= 1) s += __shfl_down(s, off, 64);
  __shared__ int ws[4];
  const int lane = threadIdx.x & 63, wid = threadIdx.x >> 6;
  if (lane == 0) ws[wid] = s;
  __syncthreads();
  if (threadIdx.x == 0)
    bsum[(size_t)t * nchunk + blockIdx.x] = ws[0] + ws[1] + ws[2] + ws[3];
}

// ---- fused scan: per-block base + intra-chunk scan; writes offs, cursor,
//      and (for lists 0,1) per-128-row bucket cursors for the partition ----
__global__ __launch_bounds__(1024) void scanfinal2_kernel(
    const int* __restrict__ counts, const int* __restrict__ bsum,
    int* __restrict__ offsets, int* __restrict__ cursor,
    int* __restrict__ bcur, int n, int nchunk) {
  const int t = blockIdx.y;
  const int* cnt = counts + (size_t)t * n;
  __shared__ int wsum[16];
  __shared__ int base_s;
  const int lane = threadIdx.x & 63, wid = threadIdx.x >> 6;
  if (wid == 0) {
    int b = (lane < blockIdx.x) ? bsum[(size_t)t * nchunk + lane] : 0;  // nchunk<=64
#pragma unroll
    for (int off = 32; off > 0; off >>= 1) b += __shfl_down(b, off, 64);
    if (lane == 0) base_s = b;
  }
  int i = blockIdx.x * 1024 + threadIdx.x;
  int v = (i < n) ? cnt[i] : 0;
  int x = v;
#pragma unroll
  for (int off = 1; off < 64; off <<= 1) {
    int u = __shfl_up(x, off, 64);
    if (lane >= off) x += u;
  }
  if (lane == 63) wsum[wid] = x;
  __syncthreads();
  if (wid == 0 && lane < 16) {
    int w = wsum[lane];
#pragma unroll
    for (int off = 1; off < 16; off <<= 1) {
      int u = __shfl_up(w, off, 16);
      if (lane >= off) w += u;
    }
    wsum[lane] = w;
  }
  __syncthreads();
  int wpre = (wid == 0) ? 0 : wsum[wid - 1];
  int val = base_s + wpre + x - v;
  if (i < n) {
    offsets[(size_t)t * (n + 1) + i] = val;
    cursor[(size_t)t * n + i] = val;
    if (i == n - 1) offsets[(size_t)t * (n + 1) + n] = val + v;
    if (t < 2 && (i & 127) == 0) bcur[t * 512 + (i >> 7)] = val;
  }
}

// ---- bucketed partition for pred/succ, two-level LDS-binned version:
//      per-block LDS counts -> one global reserve per non-empty bucket ->
//      scatter packed edges into reserved ranges ----
struct Part2Args {
  const int *dst0, *src0, *dst1, *src1;
  int* bcur;            // [2*512]
  unsigned *scr0, *scr1;
  int E;
};

__global__ __launch_bounds__(256) void partition2b_kernel(Part2Args P) {
  __shared__ int lcnt[512];
  __shared__ int lbase[512];
  const int* dst = blockIdx.y ? P.dst1 : P.dst0;
  const int* src = blockIdx.y ? P.src1 : P.src0;
  unsigned* scr = blockIdx.y ? P.scr1 : P.scr0;
  int* bcur = P.bcur + blockIdx.y * 512;
  const int tid = threadIdx.x;
  lcnt[tid] = 0;
  lcnt[tid + 256] = 0;
  __syncthreads();
  const int e0 = blockIdx.x * 4096 + tid * 16;
  unsigned pk[16];
  int slot[16];
  int cnt = 0;
#pragma unroll
  for (int k = 0; k < 16; ++k) {
    int e = e0 + k;
    if (e < P.E) {
      int d = dst[e];
      pk[k] = ((unsigned)d << 16) | (unsigned)src[e];
      slot[k] = atomicAdd(&lcnt[d >> 7], 1);
      cnt = k + 1;
    }
  }
  __syncthreads();
  {
    int c0 = lcnt[tid];
    lbase[tid] = (c0 > 0) ? atomicAdd(&bcur[tid], c0) : 0;
    int c1 = lcnt[tid + 256];
    lbase[tid + 256] = (c1 > 0) ? atomicAdd(&bcur[tid + 256], c1) : 0;
  }
  __syncthreads();
#pragma unroll
  for (int k = 0; k < 16; ++k) {
    if (k < cnt) {
      int b = (int)(pk[k] >> 23);  // (d>>7)
      scr[lbase[b] + slot[k]] = pk[k];
    }
  }
}

// ---- local fill: one block per 128-row bucket; col writes land in an ~8 KB
//      window -> L2-dense ----
struct FillLocalArgs {
  const unsigned *scr0, *scr1;
  const int *offs0, *offs1;
  int *cur0, *cur1;
  int *col0, *col1;
  int n;
};

__global__ __launch_bounds__(256) void filllocal_kernel(FillLocalArgs F) {
  const unsigned* scr = blockIdx.y ? F.scr1 : F.scr0;
  const int* offs = blockIdx.y ? F.offs1 : F.offs0;
  int* cur = blockIdx.y ? F.cur1 : F.cur0;
  int* col = blockIdx.y ? F.col1 : F.col0;
  int r0 = blockIdx.x << 7;
  int r1 = r0 + 128;
  if (r1 > F.n) r1 = F.n;
  int beg = offs[r0], end = offs[r1];
  for (int i = beg + (int)threadIdx.x; i < end; i += 256) {
    unsigned pk = scr[i];
    int d = (int)(pk >> 16);
    int s = (int)(pk & 0xffffu);
    int p = atomicAdd(&cur[d], 1);
    col[p] = s;
  }
}

// vectorized fill: 4 edges/thread (used for the small res/mat lists)
__global__ __launch_bounds__(256) void fill4v_kernel(EdgeLists4 ls) {
  EdgeList l = ls.l[blockIdx.y];
  int e0 = (blockIdx.x * 256 + threadIdx.x) * 4;
  if (e0 + 4 <= l.E) {
    int4 d = *reinterpret_cast<const int4*>(l.dst + e0);
    int4 s = *reinterpret_cast<const int4*>(l.src + e0);
    int p0 = atomicAdd(&l.counts[d.x], 1);
    int p1 = atomicAdd(&l.counts[d.y], 1);
    int p2 = atomicAdd(&l.counts[d.z], 1);
    int p3 = atomicAdd(&l.counts[d.w], 1);
    l.col[p0] = s.x;
    l.col[p1] = s.y;
    l.col[p2] = s.z;
    l.col[p3] = s.w;
  } else {
    for (int e = e0; e < l.E; ++e) {
      int p = atomicAdd(&l.counts[l.dst[e]], 1);
      l.col[p] = l.src[e];
    }
  }
}

// ---------------------------------------------------------------------------
// Aggregate device bodies (proven R12 logic, verbatim)
// ---------------------------------------------------------------------------
__device__ __forceinline__ void agg128_dev(
    const bf16* __restrict__ tab, const int* __restrict__ col,
    const int* __restrict__ offs, bf16* __restrict__ out, int n) {
  const int lane = threadIdx.x & 63;
  const int wid = threadIdx.x >> 6;
  const int r = blockIdx.x * 4 + wid;
  if (r >= n) return;
  const int slot = lane >> 4, lp = lane & 15;
  const int beg = offs[r], end = offs[r + 1];
  float acc[8] = {0.f, 0.f, 0.f, 0.f, 0.f, 0.f, 0.f, 0.f};
  float acc2[8] = {0.f, 0.f, 0.f, 0.f, 0.f, 0.f, 0.f, 0.f};
  float acc3[8] = {0.f, 0.f, 0.f, 0.f, 0.f, 0.f, 0.f, 0.f};
  float acc4[8] = {0.f, 0.f, 0.f, 0.f, 0.f, 0.f, 0.f, 0.f};
  int e = beg;
  for (; e + 16 <= end; e += 16) {
    int c0 = col[e + slot];
    int c1 = col[e + 4 + slot];
    int c2 = col[e + 8 + slot];
    int c3 = col[e + 12 + slot];
    short8 v0 = *reinterpret_cast<const short8*>(tab + (size_t)c0 * 128 + lp * 8);
    short8 v1 = *reinterpret_cast<const short8*>(tab + (size_t)c1 * 128 + lp * 8);
    short8 v2 = *reinterpret_cast<const short8*>(tab + (size_t)c2 * 128 + lp * 8);
    short8 v3 = *reinterpret_cast<const short8*>(tab + (size_t)c3 * 128 + lp * 8);
#pragma unroll
    for (int j = 0; j < 8; ++j) {
      acc[j] += bf2f(v0[j]);
      acc2[j] += bf2f(v1[j]);
      acc3[j] += bf2f(v2[j]);
      acc4[j] += bf2f(v3[j]);
    }
  }
  for (; e + 8 <= end; e += 8) {
    int c0 = col[e + slot];
    int c1 = col[e + 4 + slot];
    short8 v0 = *reinterpret_cast<const short8*>(tab + (size_t)c0 * 128 + lp * 8);
    short8 v1 = *reinterpret_cast<const short8*>(tab + (size_t)c1 * 128 + lp * 8);
#pragma unroll
    for (int j = 0; j < 8; ++j) {
      acc[j] += bf2f(v0[j]);
      acc2[j] += bf2f(v1[j]);
    }
  }
  for (; e < end; e += 4) {
    int idx = e + slot;
    if (idx < end) {
      int cc = col[idx];
      short8 v = *reinterpret_cast<const short8*>(tab + (size_t)cc * 128 + lp * 8);
#pragma unroll
      for (int j = 0; j < 8; ++j) acc[j] += bf2f(v[j]);
    }
  }
#pragma unroll
  for (int j = 0; j < 8; ++j) acc[j] = (acc[j] + acc2[j]) + (acc3[j] + acc4[j]);
#pragma unroll
  for (int j = 0; j < 8; ++j) {
    acc[j] += __shfl_xor(acc[j], 16, 64);
    acc[j] += __shfl_xor(acc[j], 32, 64);
  }
  if (slot == 0) {
    short8 sv;
#pragma unroll
    for (int j = 0; j < 8; ++j) sv[j] = f2bf(acc[j]);
    *reinterpret_cast<short8*>(out + (size_t)r * 128 + lp * 8) = sv;
  }
}

template <int D, int LPR>
__device__ __forceinline__ void agg_small_dev(
    const float* __restrict__ tab, const int* __restrict__ col,
    const int* __restrict__ offsets, bf16* __restrict__ out, int n) {
  constexpr int RPB = 256 / LPR;
  const int lane = threadIdx.x % LPR;
  const int r = blockIdx.x * RPB + threadIdx.x / LPR;
  if (r >= n) return;
  const int beg = offsets[r], end = offsets[r + 1];
  float2 acc = make_float2(0.f, 0.f);
  for (int e = beg; e < end; ++e) {
    int s = col[e];
    float2 v = *reinterpret_cast<const float2*>(tab + (size_t)s * D + lane * 2);
    acc.x += v.x;
    acc.y += v.y;
  }
  unsigned u = (unsigned)(unsigned short)f2bf(acc.x) |
               ((unsigned)(unsigned short)f2bf(acc.y) << 16);
  *reinterpret_cast<unsigned*>(out + (size_t)r * D + lane * 2) = u;
}

// merged aggregate: y=0 pred, y=1 succ, y=2 res, y=3 mat
struct AggArgs {
  const bf16* ops_tab;
  const float* res_tab;
  const float* mat_tab;
  const int *col_pred, *col_succ, *col_res, *col_mat;
  const int *offs_pred, *offs_succ, *offs_res, *offs_mat;
  bf16 *agg_pred, *agg_succ, *agg_res, *agg_mat;
  int n;
};

__global__ __launch_bounds__(256) void agg_all_kernel(AggArgs A) {
  switch (blockIdx.y) {
    case 0: agg128_dev(A.ops_tab, A.col_pred, A.offs_pred, A.agg_pred, A.n); break;
    case 1: agg128_dev(A.ops_tab, A.col_succ, A.offs_succ, A.agg_succ, A.n); break;
    case 2: agg_small_dev<64, 32>(A.res_tab, A.col_res, A.offs_res, A.agg_res, A.n); break;
    default: agg_small_dev<32, 16>(A.mat_tab, A.col_mat, A.offs_mat, A.agg_mat, A.n); break;
  }
}

// ---------------------------------------------------------------------------
// MFMA fused 2-layer MLP device body (bf16 in, bf16 out, wave-private LDS)
// FROZEN AT R8 — byte-for-byte. Do NOT restructure (R5/R6/R9/R10 all failed).
// ---------------------------------------------------------------------------
template <int K, int O, bool GATHER>
__device__ __forceinline__ void mlp2_dev(
    const bf16* __restrict__ X, const int* __restrict__ gidx,
    const short* __restrict__ W1f, const float* __restrict__ B1,
    const short* __restrict__ W2f, const float* __restrict__ B2,
    bf16* __restrict__ xbuf, int ooff, int tile, int lane, char* hw) {
  constexpr int KC = K / 32;
  constexpr int KC2 = 8;
  constexpr int OT = O / 16;
  const int g = lane >> 4, lp = lane & 15;
  const int row0 = tile * 16;

  short8 a[KC];
  {
    int srow = GATHER ? gidx[row0 + lp] : (row0 + lp);
    const bf16* xp = X + (size_t)srow * K + g * 8;
#pragma unroll
    for (int kc = 0; kc < KC; ++kc)
      a[kc] = *reinterpret_cast<const short8*>(xp + kc * 32);
  }

#pragma unroll
  for (int ct = 0; ct < 16; ++ct) {
    float bv = B1[ct * 16 + lp];
    f32x4 acc = {bv, bv, bv, bv};
#pragma unroll
    for (int kc = 0; kc < KC; ++kc) {
      short8 b = *reinterpret_cast<const short8*>(
          W1f + ((size_t)(kc * 16 + ct) * 64 + lane) * 8);
      acc = __builtin_amdgcn_mfma_f32_16x16x32_bf16(a[kc], b, acc, 0, 0, 0);
    }
#pragma unroll
    for (int r = 0; r < 4; ++r) {
      int rr = g * 4 + r;
      int byte = rr * 512 + (ct * 16 + lp) * 2;
      byte ^= (rr & 7) << 4;
      *reinterpret_cast<short*>(hw + byte) = f2bf(fmaxf(acc[r], 0.f));
    }
  }
  asm volatile("s_waitcnt lgkmcnt(0)" ::: "memory");
  __builtin_amdgcn_sched_barrier(0);

  short8 a2[KC2];
#pragma unroll
  for (int kc = 0; kc < KC2; ++kc) {
    int byte = lp * 512 + (kc * 32 + g * 8) * 2;
    byte ^= (lp & 7) << 4;
    a2[kc] = *reinterpret_cast<const short8*>(hw + byte);
  }
#pragma unroll
  for (int ot = 0; ot < OT; ++ot) {
    float bv = B2[ot * 16 + lp];
    f32x4 acc = {bv, bv, bv, bv};
#pragma unroll
    for (int kc = 0; kc < KC2; ++kc) {
      short8 b = *reinterpret_cast<const short8*>(
          W2f + ((size_t)(kc * OT + ot) * 64 + lane) * 8);
      acc = __builtin_amdgcn_mfma_f32_16x16x32_bf16(a2[kc], b, acc, 0, 0, 0);
    }
#pragma unroll
    for (int r = 0; r < 4; ++r) {
      int rr = g * 4 + r;
      *reinterpret_cast<short*>(xbuf + (size_t)(row0 + rr) * 608 + ooff + ot * 16 + lp) =
          f2bf(acc[r]);
    }
  }
}

struct Mlp6Args {
  const bf16 *agg_pred, *agg_succ, *agg_res, *agg_mat, *items_bf, *ops_bf;
  const int* related;
  const short* wf;
  const float *b_pred1, *b_pred2, *b_succ1, *b_succ2, *b_res1, *b_res2;
  const float *b_mat1, *b_mat2, *b_item1, *b_item2, *b_self1, *b_self2;
  bf16* xbuf;
  int ntiles;
};

__global__ __launch_bounds__(256) void mlp6_kernel(Mlp6Args A) {
  __shared__ short hbuf[4 * 16 * 256];  // 32 KB, 8 KB/wave
  const int lane = threadIdx.x & 63, wid = threadIdx.x >> 6;
  int tile = blockIdx.x * 4 + wid;
  if (tile >= A.ntiles) tile = A.ntiles - 1;  // dup benign
  char* hw = (char*)(hbuf + wid * (16 * 256));
  const short* wf = A.wf;
  switch (blockIdx.y) {
    case 0: mlp2_dev<128, 128, false>(A.agg_pred, nullptr, wf + 65536, A.b_pred1,
                                      wf + 221184, A.b_pred2, A.xbuf, 0, tile, lane, hw); break;
    case 1: mlp2_dev<128, 128, false>(A.agg_succ, nullptr, wf + 98304, A.b_succ1,
                                      wf + 253952, A.b_succ2, A.xbuf, 128, tile, lane, hw); break;
    case 2: mlp2_dev<64, 64, false>(A.agg_res, nullptr, wf + 131072, A.b_res1,
                                    wf + 286720, A.b_res2, A.xbuf, 256, tile, lane, hw); break;
    case 3: mlp2_dev<32, 32, false>(A.agg_mat, nullptr, wf + 147456, A.b_mat1,
                                    wf + 303104, A.b_mat2, A.xbuf, 320, tile, lane, hw); break;
    case 4: mlp2_dev<128, 128, true>(A.items_bf, A.related, wf + 32768, A.b_item1,
                                     wf + 188416, A.b_item2, A.xbuf, 352, tile, lane, hw); break;
    default: mlp2_dev<128, 128, false>(A.ops_bf, nullptr, wf + 0, A.b_self1,
                                       wf + 155648, A.b_self2, A.xbuf, 480, tile, lane, hw); break;
  }
}

// ---------------------------------------------------------------------------
// Final combiner: FROZEN AT R8 — byte-for-byte.
// ---------------------------------------------------------------------------
__global__ __launch_bounds__(256, 4) void final_kernel(
    const bf16* __restrict__ xbuf,
    const short* __restrict__ Wc1f, const float* __restrict__ B1,
    const short* __restrict__ Wc2f, const float* __restrict__ B2,
    const float* __restrict__ W3, const float* __restrict__ B3,
    float* __restrict__ out, int ntiles) {
  __shared__ short hbuf[4 * 16 * 256];  // 32 KB: per-wave h1 bf16, then h2 f32 aliased
  const int lane = threadIdx.x & 63, wid = threadIdx.x >> 6;
  int tile = blockIdx.x * 4 + wid;
  if (tile >= ntiles) tile = ntiles - 1;
  const int g = lane >> 4, lp = lane & 15;
  const int row0 = tile * 16;
  char* hw = (char*)(hbuf + wid * (16 * 256));

  // ---- L1: h1 = relu(x @ Wc1 + b1), 608->256, MFMA ----
  {
    const bf16* xp = xbuf + (size_t)(row0 + lp) * 608 + g * 8;
    short8 a[19];
#pragma unroll
    for (int kc = 0; kc < 19; ++kc)
      a[kc] = *reinterpret_cast<const short8*>(xp + kc * 32);
#pragma unroll
    for (int ct = 0; ct < 16; ++ct) {
      float bv = B1[ct * 16 + lp];
      f32x4 acc = {bv, bv, bv, bv};
#pragma unroll
      for (int kc = 0; kc < 19; ++kc) {
        short8 b = *reinterpret_cast<const short8*>(
            Wc1f + ((size_t)(kc * 16 + ct) * 64 + lane) * 8);
        acc = __builtin_amdgcn_mfma_f32_16x16x32_bf16(a[kc], b, acc, 0, 0, 0);
      }
#pragma unroll
      for (int r = 0; r < 4; ++r) {
        int rr = g * 4 + r;
        int byte = rr * 512 + (ct * 16 + lp) * 2;
        byte ^= (rr & 7) << 4;
        *reinterpret_cast<short*>(hw + byte) = f2bf(fmaxf(acc[r], 0.f));
      }
    }
  }
  asm volatile("s_waitcnt lgkmcnt(0)" ::: "memory");
  __builtin_amdgcn_sched_barrier(0);

  // ---- L2: h2 = relu(h1 @ Wc2 + b2), 256->128, MFMA ----
  {
    short8 a2[8];
#pragma unroll
    for (int kc = 0; kc < 8; ++kc) {
      int byte = lp * 512 + (kc * 32 + g * 8) * 2;
      byte ^= (lp & 7) << 4;
      a2[kc] = *reinterpret_cast<const short8*>(hw + byte);
    }
    asm volatile("s_waitcnt lgkmcnt(0)" ::: "memory");
    __builtin_amdgcn_sched_barrier(0);
    float* h2 = (float*)hw;  // alias over h1 (a2 fully in regs)
#pragma unroll
    for (int ot = 0; ot < 8; ++ot) {
      float bv = B2[ot * 16 + lp];
      f32x4 acc = {bv, bv, bv, bv};
#pragma unroll
      for (int kc = 0; kc < 8; ++kc) {
        short8 b = *reinterpret_cast<const short8*>(
            Wc2f + ((size_t)(kc * 8 + ot) * 64 + lane) * 8);
        acc = __builtin_amdgcn_mfma_f32_16x16x32_bf16(a2[kc], b, acc, 0, 0, 0);
      }
#pragma unroll
      for (int r = 0; r < 4; ++r)
        h2[(g * 4 + r) * 128 + ot * 16 + lp] = fmaxf(acc[r], 0.f);
    }
  }
  asm volatile("s_waitcnt lgkmcnt(0)" ::: "memory");
  __builtin_amdgcn_sched_barrier(0);

  // ---- L3: out = h2 @ W3 + b3, f32 VALU (precision-critical) ----
  {
    const float* h2 = (const float*)hw;
    const int half = lane >> 5;
    const int c = (lane & 31) * 4;
    const int rbase = half * 8;
    f32x4 acc3[8];
    f32x4 bv = *reinterpret_cast<const f32x4*>(B3 + c);
#pragma unroll
    for (int rr = 0; rr < 8; ++rr) acc3[rr] = bv;
    for (int k0 = 0; k0 < 128; k0 += 4) {
      f32x4 w0 = *reinterpret_cast<const f32x4*>(W3 + (size_t)(k0 + 0) * 128 + c);
      f32x4 w1 = *reinterpret_cast<const f32x4*>(W3 + (size_t)(k0 + 1) * 128 + c);
      f32x4 w2v = *reinterpret_cast<const f32x4*>(W3 + (size_t)(k0 + 2) * 128 + c);
      f32x4 w3v = *reinterpret_cast<const f32x4*>(W3 + (size_t)(k0 + 3) * 128 + c);
#pragma unroll
      for (int rr = 0; rr < 8; ++rr) {
        f32x4 h = *reinterpret_cast<const f32x4*>(&h2[(rbase + rr) * 128 + k0]);
        acc3[rr] += h.x * w0 + h.y * w1 + h.z * w2v + h.w * w3v;
      }
    }
#pragma unroll
    for (int rr = 0; rr < 8; ++rr)
      *reinterpret_cast<f32x4*>(out + (size_t)(row0 + rbase + rr) * 128 + c) = acc3[rr];
  }
}

// ---------------------------------------------------------------------------
// kernel_launch
// ---------------------------------------------------------------------------
extern "C" void kernel_launch(void* const* d_in, const int* in_sizes, int n_in,
                              void* d_out, int out_size, void* d_ws,
                              size_t ws_size, hipStream_t stream) {
  const float* operations = (const float*)d_in[0];
  const float* items      = (const float*)d_in[1];
  const float* materials  = (const float*)d_in[2];
  const float* resources  = (const float*)d_in[3];
  const int* related      = (const int*)d_in[4];
  const int* res_op       = (const int*)d_in[5];
  const int* res_res      = (const int*)d_in[6];
  const int* mat_op       = (const int*)d_in[7];
  const int* mat_mat      = (const int*)d_in[8];
  const int* prec_src     = (const int*)d_in[9];
  const int* prec_dst     = (const int*)d_in[10];
  const float* w_self1 = (const float*)d_in[11];
  const float* b_self1 = (const float*)d_in[12];
  const float* w_self2 = (const float*)d_in[13];
  const float* b_self2 = (const float*)d_in[14];
  const float* w_item1 = (const float*)d_in[15];
  const float* b_item1 = (const float*)d_in[16];
  const float* w_item2 = (const float*)d_in[17];
  const float* b_item2 = (const float*)d_in[18];
  const float* w_pred1 = (const float*)d_in[19];
  const float* b_pred1 = (const float*)d_in[20];
  const float* w_pred2 = (const float*)d_in[21];
  const float* b_pred2 = (const float*)d_in[22];
  const float* w_succ1 = (const float*)d_in[23];
  const float* b_succ1 = (const float*)d_in[24];
  const float* w_succ2 = (const float*)d_in[25];
  const float* b_succ2 = (const float*)d_in[26];
  const float* w_res1  = (const float*)d_in[27];
  const float* b_res1  = (const float*)d_in[28];
  const float* w_res2  = (const float*)d_in[29];
  const float* b_res2  = (const float*)d_in[30];
  const float* w_mat1  = (const float*)d_in[31];
  const float* b_mat1  = (const float*)d_in[32];
  const float* w_mat2  = (const float*)d_in[33];
  const float* b_mat2  = (const float*)d_in[34];
  const float* w_c1    = (const float*)d_in[35];
  const float* b_c1    = (const float*)d_in[36];
  const float* w_c2    = (const float*)d_in[37];
  const float* b_c2    = (const float*)d_in[38];
  const float* w_c3    = (const float*)d_in[39];
  const float* b_c3    = (const float*)d_in[40];

  const int N = in_sizes[0] / 128;   // 50000
  const int NI = in_sizes[1] / 128;  // 20000
  const int E_RES = in_sizes[5];
  const int E_MAT = in_sizes[7];
  const int E_PREC = in_sizes[9];

  // ---- ws layout ----
  size_t off = 0;
  auto take = [&](size_t bytes) {
    size_t o = off;
    off += (bytes + 63) & ~(size_t)63;
    return o;
  };
  size_t xbuf_off  = take((size_t)N * 608 * 2);
  size_t aggp_off  = take((size_t)N * 128 * 2);
  size_t aggsu_off = take((size_t)N * 128 * 2);
  size_t aggr_off  = take((size_t)N * 64 * 2);
  size_t aggm_off  = take((size_t)N * 32 * 2);
  size_t wf_off    = take((size_t)499712 * 2);
  size_t opsb_off  = take((size_t)N * 128 * 2);
  size_t itemb_off = take((size_t)NI * 128 * 2);
  size_t offs_off  = take((size_t)4 * (N + 1) * 4);
  size_t tmp_off   = take((size_t)4 * N * 4);
  size_t cols_off  = take(((size_t)2 * E_PREC + E_RES + E_MAT) * 4);
  size_t bsum_off  = take((size_t)4 * 64 * 4);
  size_t bcur_off  = take((size_t)2 * 512 * 4);
  size_t scr_off   = take((size_t)2 * E_PREC * 4);

  char* ws = (char*)d_ws;
  bf16* xbuf = (bf16*)(ws + xbuf_off);
  bf16* agg_pred = (bf16*)(ws + aggp_off);
  bf16* agg_succ = (bf16*)(ws + aggsu_off);
  bf16* agg_res  = (bf16*)(ws + aggr_off);
  bf16* agg_mat  = (bf16*)(ws + aggm_off);
  short* wf = (short*)(ws + wf_off);
  bf16* ops_bf   = (bf16*)(ws + opsb_off);
  bf16* items_bf = (bf16*)(ws + itemb_off);
  int* offs = (int*)(ws + offs_off);
  int* tmp  = (int*)(ws + tmp_off);
  int* cols = (int*)(ws + cols_off);
  int* bsum = (int*)(ws + bsum_off);
  int* bcur = (int*)(ws + bcur_off);
  unsigned* scr = (unsigned*)(ws + scr_off);

  int* offs_pred = offs;
  int* offs_succ = offs + (N + 1);
  int* offs_res  = offs + 2 * (N + 1);
  int* offs_mat  = offs + 3 * (N + 1);
  int* cur_pred = tmp;
  int* cur_succ = tmp + N;
  int* cur_res  = tmp + 2 * N;
  int* cur_mat  = tmp + 3 * N;
  int* col_pred = cols;
  int* col_succ = col_pred + E_PREC;
  int* col_res  = col_succ + E_PREC;
  int* col_mat  = col_res + E_RES;
  unsigned* scr_pred = scr;
  unsigned* scr_succ = scr + E_PREC;

  dim3 blk(256);

  // ---- fused preprocessing: cvt ops/items + wconv + zero tmp ----
  PrepArgs pp;
  pp.ops_src = operations; pp.ops_dst = ops_bf; pp.nops4 = N * 128 / 4;
  pp.items_src = items; pp.items_dst = items_bf; pp.nitems4 = NI * 128 / 4;
  pp.wd.w[0]  = {w_self1, 128, 256, 0};
  pp.wd.w[1]  = {w_item1, 128, 256, 32768};
  pp.wd.w[2]  = {w_pred1, 128, 256, 65536};
  pp.wd.w[3]  = {w_succ1, 128, 256, 98304};
  pp.wd.w[4]  = {w_res1,   64, 256, 131072};
  pp.wd.w[5]  = {w_mat1,   32, 256, 147456};
  pp.wd.w[6]  = {w_self2, 256, 128, 155648};
  pp.wd.w[7]  = {w_item2, 256, 128, 188416};
  pp.wd.w[8]  = {w_pred2, 256, 128, 221184};
  pp.wd.w[9]  = {w_succ2, 256, 128, 253952};
  pp.wd.w[10] = {w_res2,  256,  64, 286720};
  pp.wd.w[11] = {w_mat2,  256,  32, 303104};
  pp.wd.w[12] = {w_c1,    608, 256, 311296};
  pp.wd.w[13] = {w_c2,    256, 128, 466944};
  pp.wf = wf;
  pp.tmp = tmp; pp.ntmp = 4 * N;
  int prepx = (pp.nops4 + 255) / 256;  // 6250, covers all slices
  prep_kernel<<<dim3(prepx, 4), blk, 0, stream>>>(pp);

  // ---- CSR build ----
  EdgeLists4 els;
  els.l[0] = {prec_src, prec_dst, cur_pred, col_pred, E_PREC};
  els.l[1] = {prec_dst, prec_src, cur_succ, col_succ, E_PREC};
  els.l[2] = {res_op, res_res, cur_res, col_res, E_RES};
  els.l[3] = {mat_op, mat_mat, cur_mat, col_mat, E_MAT};
  int cgx = (E_PREC / 4 + 255) / 256;  // 4 edges/thread
  count4v_kernel<<<dim3(cgx, 4), blk, 0, stream>>>(els);
  int nchunk = (N + 1023) / 1024;  // 49
  chunksum_kernel<<<dim3(nchunk, 4), blk, 0, stream>>>(tmp, bsum, N, nchunk);
  scanfinal2_kernel<<<dim3(nchunk, 4), dim3(1024), 0, stream>>>(
      tmp, bsum, offs, tmp, bcur, N, nchunk);

  // bucketed fill for pred/succ (LDS-binned partition, low-contention)
  Part2Args pa;
  pa.dst0 = prec_src; pa.src0 = prec_dst;
  pa.dst1 = prec_dst; pa.src1 = prec_src;
  pa.bcur = bcur; pa.scr0 = scr_pred; pa.scr1 = scr_succ; pa.E = E_PREC;
  int pgx = (E_PREC + 4095) / 4096;  // 196
  partition2b_kernel<<<dim3(pgx, 2), blk, 0, stream>>>(pa);
  int nbuckets = (N + 127) / 128;  // 391
  FillLocalArgs fl;
  fl.scr0 = scr_pred; fl.scr1 = scr_succ;
  fl.offs0 = offs_pred; fl.offs1 = offs_succ;
  fl.cur0 = cur_pred; fl.cur1 = cur_succ;
  fl.col0 = col_pred; fl.col1 = col_succ;
  fl.n = N;
  filllocal_kernel<<<dim3(nbuckets, 2), blk, 0, stream>>>(fl);

  // small lists: direct fill
  EdgeLists4 els2;
  els2.l[0] = {res_op, res_res, cur_res, col_res, E_RES};
  els2.l[1] = {mat_op, mat_mat, cur_mat, col_mat, E_MAT};
  els2.l[2] = els2.l[0];
  els2.l[3] = els2.l[1];
  int cgx2 = (E_RES / 4 + 255) / 256;
  fill4v_kernel<<<dim3(cgx2, 2), blk, 0, stream>>>(els2);

  // ---- aggregates ----
  AggArgs aa;
  aa.ops_tab = ops_bf; aa.res_tab = resources; aa.mat_tab = materials;
  aa.col_pred = col_pred; aa.col_succ = col_succ; aa.col_res = col_res; aa.col_mat = col_mat;
  aa.offs_pred = offs_pred; aa.offs_succ = offs_succ; aa.offs_res = offs_res; aa.offs_mat = offs_mat;
  aa.agg_pred = agg_pred; aa.agg_succ = agg_succ; aa.agg_res = agg_res; aa.agg_mat = agg_mat;
  aa.n = N;
  agg_all_kernel<<<dim3((N + 3) / 4, 4), blk, 0, stream>>>(aa);

  // ---- 6 MLPs in one launch ----
  int ntiles = N / 16;           // 3125
  int mgrid = (ntiles + 3) / 4;  // 782
  Mlp6Args ma;
  ma.agg_pred = agg_pred; ma.agg_succ = agg_succ; ma.agg_res = agg_res; ma.agg_mat = agg_mat;
  ma.items_bf = items_bf; ma.ops_bf = ops_bf; ma.related = related; ma.wf = wf;
  ma.b_pred1 = b_pred1; ma.b_pred2 = b_pred2; ma.b_succ1 = b_succ1; ma.b_succ2 = b_succ2;
  ma.b_res1 = b_res1; ma.b_res2 = b_res2; ma.b_mat1 = b_mat1; ma.b_mat2 = b_mat2;
  ma.b_item1 = b_item1; ma.b_item2 = b_item2; ma.b_self1 = b_self1; ma.b_self2 = b_self2;
  ma.xbuf = xbuf; ma.ntiles = ntiles;
  mlp6_kernel<<<dim3(mgrid, 6), blk, 0, stream>>>(ma);

  // ---- final combiner ----
  final_kernel<<<mgrid, blk, 0, stream>>>(
      xbuf, wf + 311296, b_c1, wf + 466944, b_c2, w_c3, b_c3, (float*)d_out, ntiles);
}

// Round 17
// 520.506 us; speedup vs baseline: 1.9095x; 1.0088x over previous
//
#include <hip/hip_runtime.h>
#include <hip/hip_bf16.h>

typedef __attribute__((ext_vector_type(8))) short short8;
typedef __attribute__((ext_vector_type(4))) float f32x4;
using bf16 = __hip_bfloat16;

// N=50000, OP=128, H=256, H2=128, OUT=128
// xbuf concat: [pred 0 | succ 128 | res 256 | mat 320 | item 352 | self 480], 608

__device__ __forceinline__ short f2bf(float f) {
  union { float f; unsigned u; } v; v.f = f;
  unsigned r = (v.u + 0x7fffu + ((v.u >> 16) & 1u)) >> 16;  // RNE
  return (short)r;
}
__device__ __forceinline__ float bf2f(short s) {
  union { unsigned u; float f; } x;
  x.u = ((unsigned)(unsigned short)s) << 16;
  return x.f;
}

// ---------------------------------------------------------------------------
// Weight descriptor (needed by prep)
// ---------------------------------------------------------------------------
struct WDesc { const float* src; int K; int C; int dstoff; };
struct WDescs14 { WDesc w[14]; };

// ---------------------------------------------------------------------------
// Fused preprocessing: y=0 cvt ops, y=1 cvt items, y=2 wconv (14 mats in x),
// y=3 zero tmp.
// ---------------------------------------------------------------------------
struct PrepArgs {
  const float* ops_src; bf16* ops_dst; int nops4;
  const float* items_src; bf16* items_dst; int nitems4;
  WDescs14 wd; short* wf;
  int* tmp; int ntmp;
};

__global__ __launch_bounds__(256) void prep_kernel(PrepArgs P) {
  const int bx = blockIdx.x;
  switch (blockIdx.y) {
    case 0: {
      int i = bx * 256 + threadIdx.x;
      if (i >= P.nops4) return;
      f32x4 v = *reinterpret_cast<const f32x4*>(P.ops_src + (size_t)i * 4);
      uint2 u;
      u.x = (unsigned)(unsigned short)f2bf(v.x) | ((unsigned)(unsigned short)f2bf(v.y) << 16);
      u.y = (unsigned)(unsigned short)f2bf(v.z) | ((unsigned)(unsigned short)f2bf(v.w) << 16);
      *reinterpret_cast<uint2*>(P.ops_dst + (size_t)i * 4) = u;
    } break;
    case 1: {
      int i = bx * 256 + threadIdx.x;
      if (i >= P.nitems4) return;
      f32x4 v = *reinterpret_cast<const f32x4*>(P.items_src + (size_t)i * 4);
      uint2 u;
      u.x = (unsigned)(unsigned short)f2bf(v.x) | ((unsigned)(unsigned short)f2bf(v.y) << 16);
      u.y = (unsigned)(unsigned short)f2bf(v.z) | ((unsigned)(unsigned short)f2bf(v.w) << 16);
      *reinterpret_cast<uint2*>(P.items_dst + (size_t)i * 4) = u;
    } break;
    case 2: {
      if (bx >= 76 * 14) return;
      WDesc d = P.wd.w[bx / 76];
      int KC = d.K >> 5, CT = d.C >> 4;
      int t = (bx % 76) * 256 + threadIdx.x;
      if (t >= KC * CT * 64) return;
      int lane = t & 63, tile = t >> 6;
      int kc = tile / CT, ct = tile - kc * CT;
      int g = lane >> 4, lp = lane & 15;
      short8 v;
#pragma unroll
      for (int j = 0; j < 8; ++j)
        v[j] = f2bf(d.src[(size_t)(kc * 32 + g * 8 + j) * d.C + ct * 16 + lp]);
      *reinterpret_cast<short8*>(P.wf + d.dstoff + (size_t)t * 8) = v;
    } break;
    default: {
      int i = bx * 256 + threadIdx.x;
      if (i < P.ntmp) P.tmp[i] = 0;
    } break;
  }
}

// ---------------------------------------------------------------------------
// CSR build structures
// ---------------------------------------------------------------------------
struct EdgeList { const int* dst; const int* src; int* counts; int* col; int E; };
struct EdgeLists4 { EdgeList l[4]; };

// vectorized: 4 edges/thread
__global__ __launch_bounds__(256) void count4v_kernel(EdgeLists4 ls) {
  EdgeList l = ls.l[blockIdx.y];
  int e0 = (blockIdx.x * 256 + threadIdx.x) * 4;
  if (e0 + 4 <= l.E) {
    int4 d = *reinterpret_cast<const int4*>(l.dst + e0);
    atomicAdd(&l.counts[d.x], 1);
    atomicAdd(&l.counts[d.y], 1);
    atomicAdd(&l.counts[d.z], 1);
    atomicAdd(&l.counts[d.w], 1);
  } else {
    for (int e = e0; e < l.E; ++e) atomicAdd(&l.counts[l.dst[e]], 1);
  }
}

// ---- per-1024-chunk RAW sums for the 4 count arrays ----
__global__ __launch_bounds__(256) void chunksum_kernel(
    const int* __restrict__ counts, int* __restrict__ bsum, int n, int nchunk) {
  const int t = blockIdx.y;
  const int* cnt = counts + (size_t)t * n;
  int base = blockIdx.x * 1024;
  int s = 0;
  for (int j = threadIdx.x; j < 1024; j += 256) {
    int i = base + j;
    if (i < n) s += cnt[i];
  }
#pragma unroll
  for (int off = 32; off > 0; off >>= 1) s += __shfl_down(s, off, 64);
  __shared__ int ws[4];
  const int lane = threadIdx.x & 63, wid = threadIdx.x >> 6;
  if (lane == 0) ws[wid] = s;
  __syncthreads();
  if (threadIdx.x == 0)
    bsum[(size_t)t * nchunk + blockIdx.x] = ws[0] + ws[1] + ws[2] + ws[3];
}

// ---- fused scan: per-block base + intra-chunk scan; writes offs, cursor,
//      and (for lists 0,1) per-128-row bucket cursors for the partition ----
__global__ __launch_bounds__(1024) void scanfinal2_kernel(
    const int* __restrict__ counts, const int* __restrict__ bsum,
    int* __restrict__ offsets, int* __restrict__ cursor,
    int* __restrict__ bcur, int n, int nchunk) {
  const int t = blockIdx.y;
  const int* cnt = counts + (size_t)t * n;
  __shared__ int wsum[16];
  __shared__ int base_s;
  const int lane = threadIdx.x & 63, wid = threadIdx.x >> 6;
  if (wid == 0) {
    int b = (lane < blockIdx.x) ? bsum[(size_t)t * nchunk + lane] : 0;  // nchunk<=64
#pragma unroll
    for (int off = 32; off > 0; off >>= 1) b += __shfl_down(b, off, 64);
    if (lane == 0) base_s = b;
  }
  int i = blockIdx.x * 1024 + threadIdx.x;
  int v = (i < n) ? cnt[i] : 0;
  int x = v;
#pragma unroll
  for (int off = 1; off < 64; off <<= 1) {
    int u = __shfl_up(x, off, 64);
    if (lane >= off) x += u;
  }
  if (lane == 63) wsum[wid] = x;
  __syncthreads();
  if (wid == 0 && lane < 16) {
    int w = wsum[lane];
#pragma unroll
    for (int off = 1; off < 16; off <<= 1) {
      int u = __shfl_up(w, off, 16);
      if (lane >= off) w += u;
    }
    wsum[lane] = w;
  }
  __syncthreads();
  int wpre = (wid == 0) ? 0 : wsum[wid - 1];
  int val = base_s + wpre + x - v;
  if (i < n) {
    offsets[(size_t)t * (n + 1) + i] = val;
    cursor[(size_t)t * n + i] = val;
    if (i == n - 1) offsets[(size_t)t * (n + 1) + n] = val + v;
    if (t < 2 && (i & 127) == 0) bcur[t * 512 + (i >> 7)] = val;
  }
}

// ---- bucketed partition for pred/succ, two-level LDS-binned version ----
struct Part2Args {
  const int *dst0, *src0, *dst1, *src1;
  int* bcur;            // [2*512]
  unsigned *scr0, *scr1;
  int E;
};

__global__ __launch_bounds__(256) void partition2b_kernel(Part2Args P) {
  __shared__ int lcnt[512];
  __shared__ int lbase[512];
  const int* dst = blockIdx.y ? P.dst1 : P.dst0;
  const int* src = blockIdx.y ? P.src1 : P.src0;
  unsigned* scr = blockIdx.y ? P.scr1 : P.scr0;
  int* bcur = P.bcur + blockIdx.y * 512;
  const int tid = threadIdx.x;
  lcnt[tid] = 0;
  lcnt[tid + 256] = 0;
  __syncthreads();
  const int e0 = blockIdx.x * 4096 + tid * 16;
  unsigned pk[16];
  int slot[16];
  int cnt = 0;
#pragma unroll
  for (int k = 0; k < 16; ++k) {
    int e = e0 + k;
    if (e < P.E) {
      int d = dst[e];
      pk[k] = ((unsigned)d << 16) | (unsigned)src[e];
      slot[k] = atomicAdd(&lcnt[d >> 7], 1);
      cnt = k + 1;
    }
  }
  __syncthreads();
  {
    int c0 = lcnt[tid];
    lbase[tid] = (c0 > 0) ? atomicAdd(&bcur[tid], c0) : 0;
    int c1 = lcnt[tid + 256];
    lbase[tid + 256] = (c1 > 0) ? atomicAdd(&bcur[tid + 256], c1) : 0;
  }
  __syncthreads();
#pragma unroll
  for (int k = 0; k < 16; ++k) {
    if (k < cnt) {
      int b = (int)(pk[k] >> 23);  // (d>>7)
      scr[lbase[b] + slot[k]] = pk[k];
    }
  }
}

// ---- merged fill: y=0/1 bucket-local fill for pred/succ; y=2/3 direct
//      vectorized fill for res/mat (overlaps in one launch) ----
struct FillAllArgs {
  const unsigned *scr0, *scr1;
  const int *offs0, *offs1;
  int *cur0, *cur1;
  int *col0, *col1;
  int n;
  EdgeList small0, small1;  // res, mat
};

__global__ __launch_bounds__(256) void fillall_kernel(FillAllArgs F) {
  const int y = blockIdx.y;
  if (y < 2) {
    const unsigned* scr = y ? F.scr1 : F.scr0;
    const int* offs = y ? F.offs1 : F.offs0;
    int* cur = y ? F.cur1 : F.cur0;
    int* col = y ? F.col1 : F.col0;
    int r0 = blockIdx.x << 7;
    if (r0 >= F.n) return;
    int r1 = r0 + 128;
    if (r1 > F.n) r1 = F.n;
    int beg = offs[r0], end = offs[r1];
    for (int i = beg + (int)threadIdx.x; i < end; i += 256) {
      unsigned pk = scr[i];
      int d = (int)(pk >> 16);
      int s = (int)(pk & 0xffffu);
      int p = atomicAdd(&cur[d], 1);
      col[p] = s;
    }
  } else {
    EdgeList l = (y == 2) ? F.small0 : F.small1;
    int e0 = (blockIdx.x * 256 + threadIdx.x) * 4;
    if (e0 >= l.E) return;
    if (e0 + 4 <= l.E) {
      int4 d = *reinterpret_cast<const int4*>(l.dst + e0);
      int4 s = *reinterpret_cast<const int4*>(l.src + e0);
      int p0 = atomicAdd(&l.counts[d.x], 1);
      int p1 = atomicAdd(&l.counts[d.y], 1);
      int p2 = atomicAdd(&l.counts[d.z], 1);
      int p3 = atomicAdd(&l.counts[d.w], 1);
      l.col[p0] = s.x;
      l.col[p1] = s.y;
      l.col[p2] = s.z;
      l.col[p3] = s.w;
    } else {
      for (int e = e0; e < l.E; ++e) {
        int p = atomicAdd(&l.counts[l.dst[e]], 1);
        l.col[p] = l.src[e];
      }
    }
  }
}

// ---------------------------------------------------------------------------
// Aggregate device bodies (proven R12 logic, verbatim)
// ---------------------------------------------------------------------------
__device__ __forceinline__ void agg128_dev(
    const bf16* __restrict__ tab, const int* __restrict__ col,
    const int* __restrict__ offs, bf16* __restrict__ out, int n) {
  const int lane = threadIdx.x & 63;
  const int wid = threadIdx.x >> 6;
  const int r = blockIdx.x * 4 + wid;
  if (r >= n) return;
  const int slot = lane >> 4, lp = lane & 15;
  const int beg = offs[r], end = offs[r + 1];
  float acc[8] = {0.f, 0.f, 0.f, 0.f, 0.f, 0.f, 0.f, 0.f};
  float acc2[8] = {0.f, 0.f, 0.f, 0.f, 0.f, 0.f, 0.f, 0.f};
  float acc3[8] = {0.f, 0.f, 0.f, 0.f, 0.f, 0.f, 0.f, 0.f};
  float acc4[8] = {0.f, 0.f, 0.f, 0.f, 0.f, 0.f, 0.f, 0.f};
  int e = beg;
  for (; e + 16 <= end; e += 16) {
    int c0 = col[e + slot];
    int c1 = col[e + 4 + slot];
    int c2 = col[e + 8 + slot];
    int c3 = col[e + 12 + slot];
    short8 v0 = *reinterpret_cast<const short8*>(tab + (size_t)c0 * 128 + lp * 8);
    short8 v1 = *reinterpret_cast<const short8*>(tab + (size_t)c1 * 128 + lp * 8);
    short8 v2 = *reinterpret_cast<const short8*>(tab + (size_t)c2 * 128 + lp * 8);
    short8 v3 = *reinterpret_cast<const short8*>(tab + (size_t)c3 * 128 + lp * 8);
#pragma unroll
    for (int j = 0; j < 8; ++j) {
      acc[j] += bf2f(v0[j]);
      acc2[j] += bf2f(v1[j]);
      acc3[j] += bf2f(v2[j]);
      acc4[j] += bf2f(v3[j]);
    }
  }
  for (; e + 8 <= end; e += 8) {
    int c0 = col[e + slot];
    int c1 = col[e + 4 + slot];
    short8 v0 = *reinterpret_cast<const short8*>(tab + (size_t)c0 * 128 + lp * 8);
    short8 v1 = *reinterpret_cast<const short8*>(tab + (size_t)c1 * 128 + lp * 8);
#pragma unroll
    for (int j = 0; j < 8; ++j) {
      acc[j] += bf2f(v0[j]);
      acc2[j] += bf2f(v1[j]);
    }
  }
  for (; e < end; e += 4) {
    int idx = e + slot;
    if (idx < end) {
      int cc = col[idx];
      short8 v = *reinterpret_cast<const short8*>(tab + (size_t)cc * 128 + lp * 8);
#pragma unroll
      for (int j = 0; j < 8; ++j) acc[j] += bf2f(v[j]);
    }
  }
#pragma unroll
  for (int j = 0; j < 8; ++j) acc[j] = (acc[j] + acc2[j]) + (acc3[j] + acc4[j]);
#pragma unroll
  for (int j = 0; j < 8; ++j) {
    acc[j] += __shfl_xor(acc[j], 16, 64);
    acc[j] += __shfl_xor(acc[j], 32, 64);
  }
  if (slot == 0) {
    short8 sv;
#pragma unroll
    for (int j = 0; j < 8; ++j) sv[j] = f2bf(acc[j]);
    *reinterpret_cast<short8*>(out + (size_t)r * 128 + lp * 8) = sv;
  }
}

template <int D, int LPR>
__device__ __forceinline__ void agg_small_dev(
    const float* __restrict__ tab, const int* __restrict__ col,
    const int* __restrict__ offsets, bf16* __restrict__ out, int n) {
  constexpr int RPB = 256 / LPR;
  const int lane = threadIdx.x % LPR;
  const int r = blockIdx.x * RPB + threadIdx.x / LPR;
  if (r >= n) return;
  const int beg = offsets[r], end = offsets[r + 1];
  float2 acc = make_float2(0.f, 0.f);
  for (int e = beg; e < end; ++e) {
    int s = col[e];
    float2 v = *reinterpret_cast<const float2*>(tab + (size_t)s * D + lane * 2);
    acc.x += v.x;
    acc.y += v.y;
  }
  unsigned u = (unsigned)(unsigned short)f2bf(acc.x) |
               ((unsigned)(unsigned short)f2bf(acc.y) << 16);
  *reinterpret_cast<unsigned*>(out + (size_t)r * D + lane * 2) = u;
}

// merged aggregate: y=0 pred, y=1 succ, y=2 res, y=3 mat
struct AggArgs {
  const bf16* ops_tab;
  const float* res_tab;
  const float* mat_tab;
  const int *col_pred, *col_succ, *col_res, *col_mat;
  const int *offs_pred, *offs_succ, *offs_res, *offs_mat;
  bf16 *agg_pred, *agg_succ, *agg_res, *agg_mat;
  int n;
};

__global__ __launch_bounds__(256) void agg_all_kernel(AggArgs A) {
  switch (blockIdx.y) {
    case 0: agg128_dev(A.ops_tab, A.col_pred, A.offs_pred, A.agg_pred, A.n); break;
    case 1: agg128_dev(A.ops_tab, A.col_succ, A.offs_succ, A.agg_succ, A.n); break;
    case 2: agg_small_dev<64, 32>(A.res_tab, A.col_res, A.offs_res, A.agg_res, A.n); break;
    default: agg_small_dev<32, 16>(A.mat_tab, A.col_mat, A.offs_mat, A.agg_mat, A.n); break;
  }
}

// ---------------------------------------------------------------------------
// MFMA fused 2-layer MLP device body (bf16 in, bf16 out, wave-private LDS)
// FROZEN AT R8 — byte-for-byte. Do NOT restructure (R5/R6/R9/R10 all failed).
// ---------------------------------------------------------------------------
template <int K, int O, bool GATHER>
__device__ __forceinline__ void mlp2_dev(
    const bf16* __restrict__ X, const int* __restrict__ gidx,
    const short* __restrict__ W1f, const float* __restrict__ B1,
    const short* __restrict__ W2f, const float* __restrict__ B2,
    bf16* __restrict__ xbuf, int ooff, int tile, int lane, char* hw) {
  constexpr int KC = K / 32;
  constexpr int KC2 = 8;
  constexpr int OT = O / 16;
  const int g = lane >> 4, lp = lane & 15;
  const int row0 = tile * 16;

  short8 a[KC];
  {
    int srow = GATHER ? gidx[row0 + lp] : (row0 + lp);
    const bf16* xp = X + (size_t)srow * K + g * 8;
#pragma unroll
    for (int kc = 0; kc < KC; ++kc)
      a[kc] = *reinterpret_cast<const short8*>(xp + kc * 32);
  }

#pragma unroll
  for (int ct = 0; ct < 16; ++ct) {
    float bv = B1[ct * 16 + lp];
    f32x4 acc = {bv, bv, bv, bv};
#pragma unroll
    for (int kc = 0; kc < KC; ++kc) {
      short8 b = *reinterpret_cast<const short8*>(
          W1f + ((size_t)(kc * 16 + ct) * 64 + lane) * 8);
      acc = __builtin_amdgcn_mfma_f32_16x16x32_bf16(a[kc], b, acc, 0, 0, 0);
    }
#pragma unroll
    for (int r = 0; r < 4; ++r) {
      int rr = g * 4 + r;
      int byte = rr * 512 + (ct * 16 + lp) * 2;
      byte ^= (rr & 7) << 4;
      *reinterpret_cast<short*>(hw + byte) = f2bf(fmaxf(acc[r], 0.f));
    }
  }
  asm volatile("s_waitcnt lgkmcnt(0)" ::: "memory");
  __builtin_amdgcn_sched_barrier(0);

  short8 a2[KC2];
#pragma unroll
  for (int kc = 0; kc < KC2; ++kc) {
    int byte = lp * 512 + (kc * 32 + g * 8) * 2;
    byte ^= (lp & 7) << 4;
    a2[kc] = *reinterpret_cast<const short8*>(hw + byte);
  }
#pragma unroll
  for (int ot = 0; ot < OT; ++ot) {
    float bv = B2[ot * 16 + lp];
    f32x4 acc = {bv, bv, bv, bv};
#pragma unroll
    for (int kc = 0; kc < KC2; ++kc) {
      short8 b = *reinterpret_cast<const short8*>(
          W2f + ((size_t)(kc * OT + ot) * 64 + lane) * 8);
      acc = __builtin_amdgcn_mfma_f32_16x16x32_bf16(a2[kc], b, acc, 0, 0, 0);
    }
#pragma unroll
    for (int r = 0; r < 4; ++r) {
      int rr = g * 4 + r;
      *reinterpret_cast<short*>(xbuf + (size_t)(row0 + rr) * 608 + ooff + ot * 16 + lp) =
          f2bf(acc[r]);
    }
  }
}

struct Mlp6Args {
  const bf16 *agg_pred, *agg_succ, *agg_res, *agg_mat, *items_bf, *ops_bf;
  const int* related;
  const short* wf;
  const float *b_pred1, *b_pred2, *b_succ1, *b_succ2, *b_res1, *b_res2;
  const float *b_mat1, *b_mat2, *b_item1, *b_item2, *b_self1, *b_self2;
  bf16* xbuf;
  int ntiles;
};

__global__ __launch_bounds__(256) void mlp6_kernel(Mlp6Args A) {
  __shared__ short hbuf[4 * 16 * 256];  // 32 KB, 8 KB/wave
  const int lane = threadIdx.x & 63, wid = threadIdx.x >> 6;
  int tile = blockIdx.x * 4 + wid;
  if (tile >= A.ntiles) tile = A.ntiles - 1;  // dup benign
  char* hw = (char*)(hbuf + wid * (16 * 256));
  const short* wf = A.wf;
  switch (blockIdx.y) {
    case 0: mlp2_dev<128, 128, false>(A.agg_pred, nullptr, wf + 65536, A.b_pred1,
                                      wf + 221184, A.b_pred2, A.xbuf, 0, tile, lane, hw); break;
    case 1: mlp2_dev<128, 128, false>(A.agg_succ, nullptr, wf + 98304, A.b_succ1,
                                      wf + 253952, A.b_succ2, A.xbuf, 128, tile, lane, hw); break;
    case 2: mlp2_dev<64, 64, false>(A.agg_res, nullptr, wf + 131072, A.b_res1,
                                    wf + 286720, A.b_res2, A.xbuf, 256, tile, lane, hw); break;
    case 3: mlp2_dev<32, 32, false>(A.agg_mat, nullptr, wf + 147456, A.b_mat1,
                                    wf + 303104, A.b_mat2, A.xbuf, 320, tile, lane, hw); break;
    case 4: mlp2_dev<128, 128, true>(A.items_bf, A.related, wf + 32768, A.b_item1,
                                     wf + 188416, A.b_item2, A.xbuf, 352, tile, lane, hw); break;
    default: mlp2_dev<128, 128, false>(A.ops_bf, nullptr, wf + 0, A.b_self1,
                                       wf + 155648, A.b_self2, A.xbuf, 480, tile, lane, hw); break;
  }
}

// ---------------------------------------------------------------------------
// Final combiner: FROZEN AT R8 — byte-for-byte.
// ---------------------------------------------------------------------------
__global__ __launch_bounds__(256, 4) void final_kernel(
    const bf16* __restrict__ xbuf,
    const short* __restrict__ Wc1f, const float* __restrict__ B1,
    const short* __restrict__ Wc2f, const float* __restrict__ B2,
    const float* __restrict__ W3, const float* __restrict__ B3,
    float* __restrict__ out, int ntiles) {
  __shared__ short hbuf[4 * 16 * 256];  // 32 KB: per-wave h1 bf16, then h2 f32 aliased
  const int lane = threadIdx.x & 63, wid = threadIdx.x >> 6;
  int tile = blockIdx.x * 4 + wid;
  if (tile >= ntiles) tile = ntiles - 1;
  const int g = lane >> 4, lp = lane & 15;
  const int row0 = tile * 16;
  char* hw = (char*)(hbuf + wid * (16 * 256));

  // ---- L1: h1 = relu(x @ Wc1 + b1), 608->256, MFMA ----
  {
    const bf16* xp = xbuf + (size_t)(row0 + lp) * 608 + g * 8;
    short8 a[19];
#pragma unroll
    for (int kc = 0; kc < 19; ++kc)
      a[kc] = *reinterpret_cast<const short8*>(xp + kc * 32);
#pragma unroll
    for (int ct = 0; ct < 16; ++ct) {
      float bv = B1[ct * 16 + lp];
      f32x4 acc = {bv, bv, bv, bv};
#pragma unroll
      for (int kc = 0; kc < 19; ++kc) {
        short8 b = *reinterpret_cast<const short8*>(
            Wc1f + ((size_t)(kc * 16 + ct) * 64 + lane) * 8);
        acc = __builtin_amdgcn_mfma_f32_16x16x32_bf16(a[kc], b, acc, 0, 0, 0);
      }
#pragma unroll
      for (int r = 0; r < 4; ++r) {
        int rr = g * 4 + r;
        int byte = rr * 512 + (ct * 16 + lp) * 2;
        byte ^= (rr & 7) << 4;
        *reinterpret_cast<short*>(hw + byte) = f2bf(fmaxf(acc[r], 0.f));
      }
    }
  }
  asm volatile("s_waitcnt lgkmcnt(0)" ::: "memory");
  __builtin_amdgcn_sched_barrier(0);

  // ---- L2: h2 = relu(h1 @ Wc2 + b2), 256->128, MFMA ----
  {
    short8 a2[8];
#pragma unroll
    for (int kc = 0; kc < 8; ++kc) {
      int byte = lp * 512 + (kc * 32 + g * 8) * 2;
      byte ^= (lp & 7) << 4;
      a2[kc] = *reinterpret_cast<const short8*>(hw + byte);
    }
    asm volatile("s_waitcnt lgkmcnt(0)" ::: "memory");
    __builtin_amdgcn_sched_barrier(0);
    float* h2 = (float*)hw;  // alias over h1 (a2 fully in regs)
#pragma unroll
    for (int ot = 0; ot < 8; ++ot) {
      float bv = B2[ot * 16 + lp];
      f32x4 acc = {bv, bv, bv, bv};
#pragma unroll
      for (int kc = 0; kc < 8; ++kc) {
        short8 b = *reinterpret_cast<const short8*>(
            Wc2f + ((size_t)(kc * 8 + ot) * 64 + lane) * 8);
        acc = __builtin_amdgcn_mfma_f32_16x16x32_bf16(a2[kc], b, acc, 0, 0, 0);
      }
#pragma unroll
      for (int r = 0; r < 4; ++r)
        h2[(g * 4 + r) * 128 + ot * 16 + lp] = fmaxf(acc[r], 0.f);
    }
  }
  asm volatile("s_waitcnt lgkmcnt(0)" ::: "memory");
  __builtin_amdgcn_sched_barrier(0);

  // ---- L3: out = h2 @ W3 + b3, f32 VALU (precision-critical) ----
  {
    const float* h2 = (const float*)hw;
    const int half = lane >> 5;
    const int c = (lane & 31) * 4;
    const int rbase = half * 8;
    f32x4 acc3[8];
    f32x4 bv = *reinterpret_cast<const f32x4*>(B3 + c);
#pragma unroll
    for (int rr = 0; rr < 8; ++rr) acc3[rr] = bv;
    for (int k0 = 0; k0 < 128; k0 += 4) {
      f32x4 w0 = *reinterpret_cast<const f32x4*>(W3 + (size_t)(k0 + 0) * 128 + c);
      f32x4 w1 = *reinterpret_cast<const f32x4*>(W3 + (size_t)(k0 + 1) * 128 + c);
      f32x4 w2v = *reinterpret_cast<const f32x4*>(W3 + (size_t)(k0 + 2) * 128 + c);
      f32x4 w3v = *reinterpret_cast<const f32x4*>(W3 + (size_t)(k0 + 3) * 128 + c);
#pragma unroll
      for (int rr = 0; rr < 8; ++rr) {
        f32x4 h = *reinterpret_cast<const f32x4*>(&h2[(rbase + rr) * 128 + k0]);
        acc3[rr] += h.x * w0 + h.y * w1 + h.z * w2v + h.w * w3v;
      }
    }
#pragma unroll
    for (int rr = 0; rr < 8; ++rr)
      *reinterpret_cast<f32x4*>(out + (size_t)(row0 + rbase + rr) * 128 + c) = acc3[rr];
  }
}

// ---------------------------------------------------------------------------
// kernel_launch
// ---------------------------------------------------------------------------
extern "C" void kernel_launch(void* const* d_in, const int* in_sizes, int n_in,
                              void* d_out, int out_size, void* d_ws,
                              size_t ws_size, hipStream_t stream) {
  const float* operations = (const float*)d_in[0];
  const float* items      = (const float*)d_in[1];
  const float* materials  = (const float*)d_in[2];
  const float* resources  = (const float*)d_in[3];
  const int* related      = (const int*)d_in[4];
  const int* res_op       = (const int*)d_in[5];
  const int* res_res      = (const int*)d_in[6];
  const int* mat_op       = (const int*)d_in[7];
  const int* mat_mat      = (const int*)d_in[8];
  const int* prec_src     = (const int*)d_in[9];
  const int* prec_dst     = (const int*)d_in[10];
  const float* w_self1 = (const float*)d_in[11];
  const float* b_self1 = (const float*)d_in[12];
  const float* w_self2 = (const float*)d_in[13];
  const float* b_self2 = (const float*)d_in[14];
  const float* w_item1 = (const float*)d_in[15];
  const float* b_item1 = (const float*)d_in[16];
  const float* w_item2 = (const float*)d_in[17];
  const float* b_item2 = (const float*)d_in[18];
  const float* w_pred1 = (const float*)d_in[19];
  const float* b_pred1 = (const float*)d_in[20];
  const float* w_pred2 = (const float*)d_in[21];
  const float* b_pred2 = (const float*)d_in[22];
  const float* w_succ1 = (const float*)d_in[23];
  const float* b_succ1 = (const float*)d_in[24];
  const float* w_succ2 = (const float*)d_in[25];
  const float* b_succ2 = (const float*)d_in[26];
  const float* w_res1  = (const float*)d_in[27];
  const float* b_res1  = (const float*)d_in[28];
  const float* w_res2  = (const float*)d_in[29];
  const float* b_res2  = (const float*)d_in[30];
  const float* w_mat1  = (const float*)d_in[31];
  const float* b_mat1  = (const float*)d_in[32];
  const float* w_mat2  = (const float*)d_in[33];
  const float* b_mat2  = (const float*)d_in[34];
  const float* w_c1    = (const float*)d_in[35];
  const float* b_c1    = (const float*)d_in[36];
  const float* w_c2    = (const float*)d_in[37];
  const float* b_c2    = (const float*)d_in[38];
  const float* w_c3    = (const float*)d_in[39];
  const float* b_c3    = (const float*)d_in[40];

  const int N = in_sizes[0] / 128;   // 50000
  const int NI = in_sizes[1] / 128;  // 20000
  const int E_RES = in_sizes[5];
  const int E_MAT = in_sizes[7];
  const int E_PREC = in_sizes[9];

  // ---- ws layout ----
  size_t off = 0;
  auto take = [&](size_t bytes) {
    size_t o = off;
    off += (bytes + 63) & ~(size_t)63;
    return o;
  };
  size_t xbuf_off  = take((size_t)N * 608 * 2);
  size_t aggp_off  = take((size_t)N * 128 * 2);
  size_t aggsu_off = take((size_t)N * 128 * 2);
  size_t aggr_off  = take((size_t)N * 64 * 2);
  size_t aggm_off  = take((size_t)N * 32 * 2);
  size_t wf_off    = take((size_t)499712 * 2);
  size_t opsb_off  = take((size_t)N * 128 * 2);
  size_t itemb_off = take((size_t)NI * 128 * 2);
  size_t offs_off  = take((size_t)4 * (N + 1) * 4);
  size_t tmp_off   = take((size_t)4 * N * 4);
  size_t cols_off  = take(((size_t)2 * E_PREC + E_RES + E_MAT) * 4);
  size_t bsum_off  = take((size_t)4 * 64 * 4);
  size_t bcur_off  = take((size_t)2 * 512 * 4);
  size_t scr_off   = take((size_t)2 * E_PREC * 4);

  char* ws = (char*)d_ws;
  bf16* xbuf = (bf16*)(ws + xbuf_off);
  bf16* agg_pred = (bf16*)(ws + aggp_off);
  bf16* agg_succ = (bf16*)(ws + aggsu_off);
  bf16* agg_res  = (bf16*)(ws + aggr_off);
  bf16* agg_mat  = (bf16*)(ws + aggm_off);
  short* wf = (short*)(ws + wf_off);
  bf16* ops_bf   = (bf16*)(ws + opsb_off);
  bf16* items_bf = (bf16*)(ws + itemb_off);
  int* offs = (int*)(ws + offs_off);
  int* tmp  = (int*)(ws + tmp_off);
  int* cols = (int*)(ws + cols_off);
  int* bsum = (int*)(ws + bsum_off);
  int* bcur = (int*)(ws + bcur_off);
  unsigned* scr = (unsigned*)(ws + scr_off);

  int* offs_pred = offs;
  int* offs_succ = offs + (N + 1);
  int* offs_res  = offs + 2 * (N + 1);
  int* offs_mat  = offs + 3 * (N + 1);
  int* cur_pred = tmp;
  int* cur_succ = tmp + N;
  int* cur_res  = tmp + 2 * N;
  int* cur_mat  = tmp + 3 * N;
  int* col_pred = cols;
  int* col_succ = col_pred + E_PREC;
  int* col_res  = col_succ + E_PREC;
  int* col_mat  = col_res + E_RES;
  unsigned* scr_pred = scr;
  unsigned* scr_succ = scr + E_PREC;

  dim3 blk(256);

  // ---- fused preprocessing: cvt ops/items + wconv + zero tmp ----
  PrepArgs pp;
  pp.ops_src = operations; pp.ops_dst = ops_bf; pp.nops4 = N * 128 / 4;
  pp.items_src = items; pp.items_dst = items_bf; pp.nitems4 = NI * 128 / 4;
  pp.wd.w[0]  = {w_self1, 128, 256, 0};
  pp.wd.w[1]  = {w_item1, 128, 256, 32768};
  pp.wd.w[2]  = {w_pred1, 128, 256, 65536};
  pp.wd.w[3]  = {w_succ1, 128, 256, 98304};
  pp.wd.w[4]  = {w_res1,   64, 256, 131072};
  pp.wd.w[5]  = {w_mat1,   32, 256, 147456};
  pp.wd.w[6]  = {w_self2, 256, 128, 155648};
  pp.wd.w[7]  = {w_item2, 256, 128, 188416};
  pp.wd.w[8]  = {w_pred2, 256, 128, 221184};
  pp.wd.w[9]  = {w_succ2, 256, 128, 253952};
  pp.wd.w[10] = {w_res2,  256,  64, 286720};
  pp.wd.w[11] = {w_mat2,  256,  32, 303104};
  pp.wd.w[12] = {w_c1,    608, 256, 311296};
  pp.wd.w[13] = {w_c2,    256, 128, 466944};
  pp.wf = wf;
  pp.tmp = tmp; pp.ntmp = 4 * N;
  int prepx = (pp.nops4 + 255) / 256;  // 6250, covers all slices
  prep_kernel<<<dim3(prepx, 4), blk, 0, stream>>>(pp);

  // ---- CSR build ----
  EdgeLists4 els;
  els.l[0] = {prec_src, prec_dst, cur_pred, col_pred, E_PREC};
  els.l[1] = {prec_dst, prec_src, cur_succ, col_succ, E_PREC};
  els.l[2] = {res_op, res_res, cur_res, col_res, E_RES};
  els.l[3] = {mat_op, mat_mat, cur_mat, col_mat, E_MAT};
  int cgx = (E_PREC / 4 + 255) / 256;  // 4 edges/thread
  count4v_kernel<<<dim3(cgx, 4), blk, 0, stream>>>(els);
  int nchunk = (N + 1023) / 1024;  // 49
  chunksum_kernel<<<dim3(nchunk, 4), blk, 0, stream>>>(tmp, bsum, N, nchunk);
  scanfinal2_kernel<<<dim3(nchunk, 4), dim3(1024), 0, stream>>>(
      tmp, bsum, offs, tmp, bcur, N, nchunk);

  // bucketed partition for pred/succ (LDS-binned, low-contention)
  Part2Args pa;
  pa.dst0 = prec_src; pa.src0 = prec_dst;
  pa.dst1 = prec_dst; pa.src1 = prec_src;
  pa.bcur = bcur; pa.scr0 = scr_pred; pa.scr1 = scr_succ; pa.E = E_PREC;
  int pgx = (E_PREC + 4095) / 4096;  // 196
  partition2b_kernel<<<dim3(pgx, 2), blk, 0, stream>>>(pa);

  // merged fill: bucket-local pred/succ + direct res/mat in one launch
  int nbuckets = (N + 127) / 128;  // 391
  FillAllArgs fa;
  fa.scr0 = scr_pred; fa.scr1 = scr_succ;
  fa.offs0 = offs_pred; fa.offs1 = offs_succ;
  fa.cur0 = cur_pred; fa.cur1 = cur_succ;
  fa.col0 = col_pred; fa.col1 = col_succ;
  fa.n = N;
  fa.small0 = {res_op, res_res, cur_res, col_res, E_RES};
  fa.small1 = {mat_op, mat_mat, cur_mat, col_mat, E_MAT};
  int cgx2 = (E_RES / 4 + 255) / 256;  // 98 <= nbuckets
  int fgx = nbuckets > cgx2 ? nbuckets : cgx2;
  fillall_kernel<<<dim3(fgx, 4), blk, 0, stream>>>(fa);

  // ---- aggregates ----
  AggArgs aa;
  aa.ops_tab = ops_bf; aa.res_tab = resources; aa.mat_tab = materials;
  aa.col_pred = col_pred; aa.col_succ = col_succ; aa.col_res = col_res; aa.col_mat = col_mat;
  aa.offs_pred = offs_pred; aa.offs_succ = offs_succ; aa.offs_res = offs_res; aa.offs_mat = offs_mat;
  aa.agg_pred = agg_pred; aa.agg_succ = agg_succ; aa.agg_res = agg_res; aa.agg_mat = agg_mat;
  aa.n = N;
  agg_all_kernel<<<dim3((N + 3) / 4, 4), blk, 0, stream>>>(aa);

  // ---- 6 MLPs in one launch ----
  int ntiles = N / 16;           // 3125
  int mgrid = (ntiles + 3) / 4;  // 782
  Mlp6Args ma;
  ma.agg_pred = agg_pred; ma.agg_succ = agg_succ; ma.agg_res = agg_res; ma.agg_mat = agg_mat;
  ma.items_bf = items_bf; ma.ops_bf = ops_bf; ma.related = related; ma.wf = wf;
  ma.b_pred1 = b_pred1; ma.b_pred2 = b_pred2; ma.b_succ1 = b_succ1; ma.b_succ2 = b_succ2;
  ma.b_res1 = b_res1; ma.b_res2 = b_res2; ma.b_mat1 = b_mat1; ma.b_mat2 = b_mat2;
  ma.b_item1 = b_item1; ma.b_item2 = b_item2; ma.b_self1 = b_self1; ma.b_self2 = b_self2;
  ma.xbuf = xbuf; ma.ntiles = ntiles;
  mlp6_kernel<<<dim3(mgrid, 6), blk, 0, stream>>>(ma);

  // ---- final combiner ----
  final_kernel<<<mgrid, blk, 0, stream>>>(
      xbuf, wf + 311296, b_c1, wf + 466944, b_c2, w_c3, b_c3, (float*)d_out, ntiles);
}